// Round 1
// baseline (510.183 us; speedup 1.0000x reference)
//
#include <hip/hip_runtime.h>
#include <hip/hip_bf16.h>
#include <stdint.h>

// ---------------------------------------------------------------------------
// MultiHeadAttention (no head split): out = softmax_causal((xWq)(xWk)^T/32) (xWv) Wo
// B=4, T=2048, C=1024, fp32 in/out, bf16 MFMA compute.
// ---------------------------------------------------------------------------

typedef __attribute__((ext_vector_type(8))) __bf16 bf16x8;
typedef __attribute__((ext_vector_type(4))) float f32x4;

#define MFMA16(A, B, C) __builtin_amdgcn_mfma_f32_16x16x32_bf16(A, B, C, 0, 0, 0)

static __device__ __forceinline__ void gload_lds16(const void* g, void* l) {
  __builtin_amdgcn_global_load_lds(
      (const __attribute__((address_space(1))) void*)g,
      (__attribute__((address_space(3))) void*)l, 16, 0, 0);
}

// ------------------------- elementwise fp32 -> bf16 ------------------------
__global__ void cvt_bf16_kernel(const float* __restrict__ in,
                                __bf16* __restrict__ out, int n8) {
  int i = blockIdx.x * blockDim.x + threadIdx.x;
  if (i < n8) {
    const float4* p = (const float4*)(in + (size_t)i * 8);
    float4 a = p[0], b = p[1];
    bf16x8 o;
    o[0] = (__bf16)a.x; o[1] = (__bf16)a.y; o[2] = (__bf16)a.z; o[3] = (__bf16)a.w;
    o[4] = (__bf16)b.x; o[5] = (__bf16)b.y; o[6] = (__bf16)b.z; o[7] = (__bf16)b.w;
    *(bf16x8*)(out + (size_t)i * 8) = o;
  }
}

// -------------------- W (K x N fp32) -> Wt (N x K bf16) --------------------
__global__ void transpose_cvt_kernel(const float* __restrict__ W,
                                     __bf16* __restrict__ Wt) {
  __shared__ float tile[32][33];
  int tx = threadIdx.x, ty = threadIdx.y;
  int bx = blockIdx.x * 32, by = blockIdx.y * 32;
#pragma unroll
  for (int i = 0; i < 4; i++)
    tile[ty + 8 * i][tx] = W[(size_t)(by + ty + 8 * i) * 1024 + bx + tx];
  __syncthreads();
#pragma unroll
  for (int i = 0; i < 4; i++)
    Wt[(size_t)(bx + ty + 8 * i) * 1024 + by + tx] = (__bf16)tile[tx][ty + 8 * i];
}

// -------------- V [b][2048][1024] bf16 -> Vt [b][1024][2048] ---------------
__global__ void transpose_v_kernel(const __bf16* __restrict__ V,
                                   __bf16* __restrict__ Vt) {
  __shared__ __bf16 tile[32][33];
  int tx = threadIdx.x, ty = threadIdx.y;
  int b = blockIdx.z;
  int t0 = blockIdx.x * 32, d0 = blockIdx.y * 32;
  const __bf16* Vb = V + (size_t)b * 2048 * 1024;
  __bf16* Vtb = Vt + (size_t)b * 1024 * 2048;
#pragma unroll
  for (int i = 0; i < 4; i++)
    tile[ty + 8 * i][tx] = Vb[(size_t)(t0 + ty + 8 * i) * 1024 + d0 + tx];
  __syncthreads();
#pragma unroll
  for (int i = 0; i < 4; i++)
    Vtb[(size_t)(d0 + ty + 8 * i) * 2048 + t0 + tx] = tile[tx][ty + 8 * i];
}

// --------------------------- GEMM: C = A @ Bt^T + bias ---------------------
// A: M x K bf16 row-major.  Bt: N x K bf16 row-major (i.e. B transposed).
// 128x128 tile, BK=32, 256 threads (4 waves in 2x2, 64x64 each), m97 structure.
template <bool OUT_F32>
__global__ __launch_bounds__(256) void gemm_bt_kernel(
    const __bf16* __restrict__ A, const __bf16* __restrict__ Bt,
    const float* __restrict__ bias, void* __restrict__ Cp, int M, int N, int K) {
  constexpr int BK = 32;
  __shared__ __align__(16) __bf16 lA[2][128 * BK];
  __shared__ __align__(16) __bf16 lB[2][128 * BK];
  const int tid = threadIdx.x;
  const int wave = tid >> 6, lane = tid & 63;
  const int bm = blockIdx.x * 128, bn = blockIdx.y * 128;
  const int wr = wave >> 1, wc = wave & 1;
  f32x4 acc[4][4] = {};

  const int srow = lane >> 2;        // 0..15 within 16-row chunk
  const int skc = (lane & 3) * 8;    // k element offset (16B chunks)

  const int NT = K / BK;
  // prologue stage
  {
#pragma unroll
    for (int i = 0; i < 2; i++) {
      int c = wave * 2 + i;
      gload_lds16(A + (size_t)(bm + c * 16 + srow) * K + skc, &lA[0][c * 512]);
      gload_lds16(Bt + (size_t)(bn + c * 16 + srow) * K + skc, &lB[0][c * 512]);
    }
  }
  __syncthreads();

  const int arow = wr * 64 + (lane & 15);
  const int brow = wc * 64 + (lane & 15);
  const int kb = (lane >> 4) * 8;
  int cur = 0;
  for (int kt = 0; kt < NT; ++kt) {
    if (kt + 1 < NT) {
      const int k0 = (kt + 1) * BK;
#pragma unroll
      for (int i = 0; i < 2; i++) {
        int c = wave * 2 + i;
        gload_lds16(A + (size_t)(bm + c * 16 + srow) * K + k0 + skc,
                    &lA[cur ^ 1][c * 512]);
        gload_lds16(Bt + (size_t)(bn + c * 16 + srow) * K + k0 + skc,
                    &lB[cur ^ 1][c * 512]);
      }
    }
    bf16x8 af[4], bfg[4];
#pragma unroll
    for (int i = 0; i < 4; i++)
      af[i] = *(const bf16x8*)&lA[cur][(arow + 16 * i) * BK + kb];
#pragma unroll
    for (int j = 0; j < 4; j++)
      bfg[j] = *(const bf16x8*)&lB[cur][(brow + 16 * j) * BK + kb];
#pragma unroll
    for (int i = 0; i < 4; i++)
#pragma unroll
      for (int j = 0; j < 4; j++)
        acc[i][j] = MFMA16(af[i], bfg[j], acc[i][j]);
    __syncthreads();
    cur ^= 1;
  }

  // epilogue: D frag row=(lane>>4)*4+r, col=lane&15
#pragma unroll
  for (int j = 0; j < 4; j++) {
    int col = bn + wc * 64 + j * 16 + (lane & 15);
    float bv = bias[col];
#pragma unroll
    for (int i = 0; i < 4; i++) {
      int rbase = bm + wr * 64 + i * 16 + (lane >> 4) * 4;
#pragma unroll
      for (int r = 0; r < 4; r++) {
        float v = acc[i][j][r] + bv;
        if (OUT_F32)
          ((float*)Cp)[(size_t)(rbase + r) * N + col] = v;
        else
          ((__bf16*)Cp)[(size_t)(rbase + r) * N + col] = (__bf16)v;
      }
    }
  }
}

// ------------------------------ flash attention ----------------------------
// 8 waves (512 thr). Q tile = 16 rows; each wave owns a 128-wide D slice.
// Causal balance: WG (b,p) processes q-tiles p and 127-p  (~constant work).
#define FT 2048
#define FD 1024
#define QBLK 16
#define KVB 32
__global__ __launch_bounds__(512) void flash_kernel(
    const __bf16* __restrict__ Q, const __bf16* __restrict__ K,
    const __bf16* __restrict__ Vt, __bf16* __restrict__ AO) {
  __shared__ float Sp[8][QBLK][33];           // per-wave partial scores
  __shared__ float Sred[QBLK][33];            // reduced scores
  __shared__ __align__(16) float alphaB[QBLK];
  __shared__ __align__(16) float linvB[QBLK];
  __shared__ __align__(16) __bf16 Pbuf[QBLK][40];
  __shared__ __align__(16) __bf16 obuf[QBLK][FD];

  const int tid = threadIdx.x;
  const int wave = tid >> 6, lane = tid & 63;
  const int b = blockIdx.x >> 6;   // batch 0..3
  const int p = blockIdx.x & 63;   // pair id 0..63
  const int dsl = wave * 128;      // this wave's D slice
  const float scale = 0.03125f;    // 1/sqrt(1024)

  for (int sub = 0; sub < 2; ++sub) {
    const int jt = (sub == 0) ? p : 127 - p;
    const int qbase = jt * QBLK;

    bf16x8 qf[4];
    {
      const __bf16* qp =
          Q + (size_t)(b * FT + qbase + (lane & 15)) * FD + dsl + (lane >> 4) * 8;
#pragma unroll
      for (int ks = 0; ks < 4; ks++) qf[ks] = *(const bf16x8*)(qp + ks * 32);
    }
    f32x4 acc[8] = {};
    float m_run = -1e30f, l_run = 0.f;  // live in wave 0 only
    const int nsteps = qbase / KVB + 1;

    for (int s = 0; s < nsteps; ++s) {
      const int kvb = s * KVB;
      // ---- QK^T partial over this wave's D slice ----
      f32x4 sp[2] = {};
#pragma unroll
      for (int cf = 0; cf < 2; ++cf) {
        const __bf16* kp = K + (size_t)(b * FT + kvb + cf * 16 + (lane & 15)) * FD +
                           dsl + (lane >> 4) * 8;
#pragma unroll
        for (int ks = 0; ks < 4; ks++) {
          bf16x8 kf = *(const bf16x8*)(kp + ks * 32);
          sp[cf] = MFMA16(qf[ks], kf, sp[cf]);
        }
      }
      // early-issue V loads (consumed after softmax)
      bf16x8 vf[8];
#pragma unroll
      for (int vfi = 0; vfi < 8; ++vfi) {
        const __bf16* vp = Vt + (size_t)b * FD * FT +
                           (size_t)(dsl + vfi * 16 + (lane & 15)) * FT + kvb +
                           (lane >> 4) * 8;
        vf[vfi] = *(const bf16x8*)vp;
      }
      // ---- write partials ----
#pragma unroll
      for (int cf = 0; cf < 2; ++cf)
#pragma unroll
        for (int r = 0; r < 4; r++)
          Sp[wave][(lane >> 4) * 4 + r][cf * 16 + (lane & 15)] = sp[cf][r];
      __syncthreads();
      // ---- cooperative cross-wave reduce (512 thr == 16x32 elems) ----
      {
        int row = tid >> 5, col = tid & 31;
        float a = 0.f;
#pragma unroll
        for (int w2 = 0; w2 < 8; ++w2) a += Sp[w2][row][col];
        Sred[row][col] = a;
      }
      __syncthreads();
      // ---- wave 0: online softmax ----
      if (wave == 0) {
        const int row = lane & 15, cg = lane >> 4;
        const int qrow = qbase + row;
        float sv[8];
        float tmax = -1e30f;
#pragma unroll
        for (int c2 = 0; c2 < 8; c2++) {
          int col = cg * 8 + c2;
          float v = Sred[row][col] * scale;
          if (kvb + col > qrow) v = -1e30f;
          sv[c2] = v;
          tmax = fmaxf(tmax, v);
        }
        tmax = fmaxf(tmax, __shfl_xor(tmax, 16));
        tmax = fmaxf(tmax, __shfl_xor(tmax, 32));
        float mnew = fmaxf(m_run, tmax);
        float alpha = __expf(m_run - mnew);
        float psum = 0.f;
#pragma unroll
        for (int c2 = 0; c2 < 8; c2++) {
          float pv = __expf(sv[c2] - mnew);
          psum += pv;
          Pbuf[row][cg * 8 + c2] = (__bf16)pv;
        }
        psum += __shfl_xor(psum, 16);
        psum += __shfl_xor(psum, 32);
        l_run = l_run * alpha + psum;
        m_run = mnew;
        if (lane < 16) alphaB[lane] = alpha;
      }
      __syncthreads();
      // ---- all waves: rescale acc, P @ V ----
      f32x4 al = *(const f32x4*)&alphaB[(lane >> 4) * 4];
      bf16x8 pf = *(const bf16x8*)&Pbuf[lane & 15][(lane >> 4) * 8];
#pragma unroll
      for (int vfi = 0; vfi < 8; ++vfi) {
#pragma unroll
        for (int r = 0; r < 4; r++) acc[vfi][r] *= al[r];
        acc[vfi] = MFMA16(pf, vf[vfi], acc[vfi]);
      }
    }

    // ---- finalize: divide by l, stage in LDS, coalesced store ----
    if (wave == 0 && lane < 16) linvB[lane] = 1.0f / l_run;
    __syncthreads();
    f32x4 li = *(const f32x4*)&linvB[(lane >> 4) * 4];
#pragma unroll
    for (int vfi = 0; vfi < 8; ++vfi)
#pragma unroll
      for (int r = 0; r < 4; r++)
        obuf[(lane >> 4) * 4 + r][dsl + vfi * 16 + (lane & 15)] =
            (__bf16)(acc[vfi][r] * li[r]);
    __syncthreads();
    for (int c2 = tid; c2 < QBLK * (FD / 8); c2 += 512) {
      int row = c2 >> 7, chunk = c2 & 127;  // 128 chunks of 8 bf16 per row
      *(int4*)(AO + (size_t)(b * FT + qbase + row) * FD + chunk * 8) =
          *(const int4*)&obuf[row][chunk * 8];
    }
    __syncthreads();
  }
}

// ---------------------------------------------------------------------------
extern "C" void kernel_launch(void* const* d_in, const int* in_sizes, int n_in,
                              void* d_out, int out_size, void* d_ws,
                              size_t ws_size, hipStream_t stream) {
  const float* x = (const float*)d_in[0];
  const float* Wq = (const float*)d_in[1];
  const float* bq = (const float*)d_in[2];
  const float* Wk = (const float*)d_in[3];
  const float* bk = (const float*)d_in[4];
  const float* Wv = (const float*)d_in[5];
  const float* bv = (const float*)d_in[6];
  const float* Wo = (const float*)d_in[7];
  const float* bo = (const float*)d_in[8];

  char* ws = (char*)d_ws;
  const size_t MB = 1u << 20;
  __bf16* xb = (__bf16*)(ws);               // 16MB  [0,16)
  __bf16* Wqt = (__bf16*)(ws + 16 * MB);    // 2MB each
  __bf16* Wkt = (__bf16*)(ws + 18 * MB);
  __bf16* Wvt = (__bf16*)(ws + 20 * MB);
  __bf16* Wot = (__bf16*)(ws + 22 * MB);
  __bf16* Qb = (__bf16*)(ws + 24 * MB);     // 16MB
  __bf16* Kb = (__bf16*)(ws + 40 * MB);     // 16MB
  __bf16* Vb = (__bf16*)(ws + 56 * MB);     // 16MB
  __bf16* Vtb = (__bf16*)(ws);              // alias xb (dead after V GEMM)
  __bf16* AOb = (__bf16*)(ws + 56 * MB);    // alias Vb (dead after transpose)
  // total ws needed: 72MB

  // 1) x -> bf16
  cvt_bf16_kernel<<<4096, 256, 0, stream>>>(x, xb, 8192 * 1024 / 8);
  // 2) weight transposes (fp32 -> bf16, N x K)
  dim3 tb(32, 8);
  transpose_cvt_kernel<<<dim3(32, 32), tb, 0, stream>>>(Wq, Wqt);
  transpose_cvt_kernel<<<dim3(32, 32), tb, 0, stream>>>(Wk, Wkt);
  transpose_cvt_kernel<<<dim3(32, 32), tb, 0, stream>>>(Wv, Wvt);
  transpose_cvt_kernel<<<dim3(32, 32), tb, 0, stream>>>(Wo, Wot);
  // 3) QKV projections
  dim3 gg(64, 8);
  gemm_bt_kernel<false><<<gg, 256, 0, stream>>>(xb, Wqt, bq, Qb, 8192, 1024, 1024);
  gemm_bt_kernel<false><<<gg, 256, 0, stream>>>(xb, Wkt, bk, Kb, 8192, 1024, 1024);
  gemm_bt_kernel<false><<<gg, 256, 0, stream>>>(xb, Wvt, bv, Vb, 8192, 1024, 1024);
  // 4) V -> V^T per batch
  transpose_v_kernel<<<dim3(64, 32, 4), tb, 0, stream>>>(Vb, Vtb);
  // 5) causal flash attention
  flash_kernel<<<256, 512, 0, stream>>>(Qb, Kb, Vtb, AOb);
  // 6) output projection (fp32 out)
  gemm_bt_kernel<true><<<gg, 256, 0, stream>>>(AOb, Wot, bo, d_out, 8192, 1024, 1024);
}

// Round 2
// 250.764 us; speedup vs baseline: 2.0345x; 2.0345x over previous
//
#include <hip/hip_runtime.h>
#include <hip/hip_bf16.h>
#include <stdint.h>

// ---------------------------------------------------------------------------
// MultiHeadAttention (no head split): out = softmax_causal((xWq)(xWk)^T/32)(xWv) Wo
// B=4, T=2048, C=1024, fp32 in/out, bf16 MFMA compute.
// Attention done as: causal GEMM S=QK^T (fp32) -> row softmax (P bf16 in-place)
//                    -> GEMM O=P V with triangular K-length.
// ---------------------------------------------------------------------------

typedef __attribute__((ext_vector_type(8))) __bf16 bf16x8;
typedef __attribute__((ext_vector_type(4))) float f32x4;

#define MFMA16(A, B, C) __builtin_amdgcn_mfma_f32_16x16x32_bf16(A, B, C, 0, 0, 0)

#define T_SEQ 2048
#define D_MOD 1024

static __device__ __forceinline__ void gload_lds16(const void* g, void* l) {
  __builtin_amdgcn_global_load_lds(
      (const __attribute__((address_space(1))) void*)g,
      (__attribute__((address_space(3))) void*)l, 16, 0, 0);
}

// ------------------------- elementwise fp32 -> bf16 ------------------------
__global__ void cvt_bf16_kernel(const float* __restrict__ in,
                                __bf16* __restrict__ out, int n8) {
  int i = blockIdx.x * blockDim.x + threadIdx.x;
  if (i < n8) {
    const float4* p = (const float4*)(in + (size_t)i * 8);
    float4 a = p[0], b = p[1];
    bf16x8 o;
    o[0] = (__bf16)a.x; o[1] = (__bf16)a.y; o[2] = (__bf16)a.z; o[3] = (__bf16)a.w;
    o[4] = (__bf16)b.x; o[5] = (__bf16)b.y; o[6] = (__bf16)b.z; o[7] = (__bf16)b.w;
    *(bf16x8*)(out + (size_t)i * 8) = o;
  }
}

// -------------------- W (K x N fp32) -> Wt (N x K bf16) --------------------
__global__ void transpose_cvt_kernel(const float* __restrict__ W,
                                     __bf16* __restrict__ Wt) {
  __shared__ float tile[32][33];
  int tx = threadIdx.x, ty = threadIdx.y;
  int bx = blockIdx.x * 32, by = blockIdx.y * 32;
#pragma unroll
  for (int i = 0; i < 4; i++)
    tile[ty + 8 * i][tx] = W[(size_t)(by + ty + 8 * i) * D_MOD + bx + tx];
  __syncthreads();
#pragma unroll
  for (int i = 0; i < 4; i++)
    Wt[(size_t)(bx + ty + 8 * i) * D_MOD + by + tx] = (__bf16)tile[tx][ty + 8 * i];
}

// -------------- V [b][2048][1024] bf16 -> Vt [b][1024][2048] ---------------
__global__ void transpose_v_kernel(const __bf16* __restrict__ V,
                                   __bf16* __restrict__ Vt) {
  __shared__ __bf16 tile[32][33];
  int tx = threadIdx.x, ty = threadIdx.y;
  int b = blockIdx.z;
  int t0 = blockIdx.x * 32, d0 = blockIdx.y * 32;
  const __bf16* Vb = V + (size_t)b * T_SEQ * D_MOD;
  __bf16* Vtb = Vt + (size_t)b * D_MOD * T_SEQ;
#pragma unroll
  for (int i = 0; i < 4; i++)
    tile[ty + 8 * i][tx] = Vb[(size_t)(t0 + ty + 8 * i) * D_MOD + d0 + tx];
  __syncthreads();
#pragma unroll
  for (int i = 0; i < 4; i++)
    Vtb[(size_t)(d0 + ty + 8 * i) * T_SEQ + t0 + tx] = tile[tx][ty + 8 * i];
}

// --------------------------- unified GEMM ----------------------------------
// C = A @ Bt^T [+bias].  A: MxK bf16 (lda).  Bt: NxK bf16 (ldb).
// 128x128 tile, BK=32, 256 threads (4 waves 2x2), double-buffered LDS,
// global_load_lds width-16 staging (m97 structure).
// MODE: 0 = proj (bias, bf16 out), 1 = out-proj (bias, f32 out),
//       2 = PV   (no bias, bf16 out, K = (blockIdx.x+1)*128),
//       3 = QK   (scale+causal mask, f32 out, skip blocks above diagonal)
template <int MODE>
__global__ __launch_bounds__(256) void gemm_kernel(
    const __bf16* __restrict__ A, const __bf16* __restrict__ Bt,
    const float* __restrict__ bias, void* __restrict__ Cp, int lda, int ldb,
    int ldc, int Kparam, size_t bsA, size_t bsB, size_t bsCbytes) {
  if (MODE == 3 && blockIdx.y > blockIdx.x) return;  // fully-masked block
  constexpr int BK = 32;
  __shared__ __align__(16) __bf16 lA[2][128 * BK];
  __shared__ __align__(16) __bf16 lB[2][128 * BK];
  const int z = blockIdx.z;
  A += (size_t)z * bsA;
  Bt += (size_t)z * bsB;
  char* Cbase = (char*)Cp + (size_t)z * bsCbytes;
  const int K = (MODE == 2) ? (int)(blockIdx.x + 1) * 128 : Kparam;

  const int tid = threadIdx.x;
  const int wave = tid >> 6, lane = tid & 63;
  const int bm = blockIdx.x * 128, bn = blockIdx.y * 128;
  const int wr = wave >> 1, wc = wave & 1;
  f32x4 acc[4][4] = {};

  const int srow = lane >> 2;      // 0..15 within 16-row chunk
  const int skc = (lane & 3) * 8;  // k element offset (16B chunks)

  const int NT = K / BK;
  {
#pragma unroll
    for (int i = 0; i < 2; i++) {
      int c = wave * 2 + i;
      gload_lds16(A + (size_t)(bm + c * 16 + srow) * lda + skc, &lA[0][c * 512]);
      gload_lds16(Bt + (size_t)(bn + c * 16 + srow) * ldb + skc, &lB[0][c * 512]);
    }
  }
  __syncthreads();

  const int arow = wr * 64 + (lane & 15);
  const int brow = wc * 64 + (lane & 15);
  const int kb = (lane >> 4) * 8;
  int cur = 0;
  for (int kt = 0; kt < NT; ++kt) {
    if (kt + 1 < NT) {
      const int k0 = (kt + 1) * BK;
#pragma unroll
      for (int i = 0; i < 2; i++) {
        int c = wave * 2 + i;
        gload_lds16(A + (size_t)(bm + c * 16 + srow) * lda + k0 + skc,
                    &lA[cur ^ 1][c * 512]);
        gload_lds16(Bt + (size_t)(bn + c * 16 + srow) * ldb + k0 + skc,
                    &lB[cur ^ 1][c * 512]);
      }
    }
    bf16x8 af[4], bfg[4];
#pragma unroll
    for (int i = 0; i < 4; i++)
      af[i] = *(const bf16x8*)&lA[cur][(arow + 16 * i) * BK + kb];
#pragma unroll
    for (int j = 0; j < 4; j++)
      bfg[j] = *(const bf16x8*)&lB[cur][(brow + 16 * j) * BK + kb];
#pragma unroll
    for (int i = 0; i < 4; i++)
#pragma unroll
      for (int j = 0; j < 4; j++)
        acc[i][j] = MFMA16(af[i], bfg[j], acc[i][j]);
    __syncthreads();
    cur ^= 1;
  }

  // epilogue: D frag row=(lane>>4)*4+r, col=lane&15
#pragma unroll
  for (int j = 0; j < 4; j++) {
    int col = bn + wc * 64 + j * 16 + (lane & 15);
    float bv = (MODE == 0 || MODE == 1) ? bias[col] : 0.0f;
#pragma unroll
    for (int i = 0; i < 4; i++) {
      int rbase = bm + wr * 64 + i * 16 + (lane >> 4) * 4;
#pragma unroll
      for (int r = 0; r < 4; r++) {
        int row = rbase + r;
        float v = acc[i][j][r];
        if (MODE == 3) {
          v *= 0.03125f;  // 1/sqrt(1024)
          if (col > row) v = -1e30f;
          ((float*)Cbase)[(size_t)row * ldc + col] = v;
        } else if (MODE == 1) {
          ((float*)Cbase)[(size_t)row * ldc + col] = v + bv;
        } else if (MODE == 0) {
          ((__bf16*)Cbase)[(size_t)row * ldc + col] = (__bf16)(v + bv);
        } else {
          ((__bf16*)Cbase)[(size_t)row * ldc + col] = (__bf16)v;
        }
      }
    }
  }
}

// ----------------------- row softmax, P bf16 in-place ----------------------
// One 256-thread WG per row. Row t: valid length L = ceil128(t+1) (masked
// entries hold -1e30 from the QK epilogue). Reads fp32, writes bf16 into the
// same buffer (P row stride = 4096 bf16 elems = S row bytes).
__global__ __launch_bounds__(256) void softmax_kernel(float* __restrict__ S,
                                                      size_t bstride) {
  const int t = blockIdx.x, b = blockIdx.y;
  float* Srow = S + (size_t)b * bstride + (size_t)t * T_SEQ;
  __bf16* Prow = (__bf16*)Srow;
  const int L = ((t + 1) + 127) & ~127;
  const int tid = threadIdx.x;
  const int base = tid * 8;
  const bool act = base < L;
  float v[8];
  float m = -1e30f;
  if (act) {
    float4 a = *(const float4*)(Srow + base);
    float4 c = *(const float4*)(Srow + base + 4);
    v[0] = a.x; v[1] = a.y; v[2] = a.z; v[3] = a.w;
    v[4] = c.x; v[5] = c.y; v[6] = c.z; v[7] = c.w;
#pragma unroll
    for (int j = 0; j < 8; j++) m = fmaxf(m, v[j]);
  }
#pragma unroll
  for (int off = 1; off < 64; off <<= 1) m = fmaxf(m, __shfl_xor(m, off));
  __shared__ float redm[4], reds[4];
  const int wave = tid >> 6, lane = tid & 63;
  if (lane == 0) redm[wave] = m;
  __syncthreads();
  m = fmaxf(fmaxf(redm[0], redm[1]), fmaxf(redm[2], redm[3]));
  float p[8];
  float s = 0.f;
  if (act) {
#pragma unroll
    for (int j = 0; j < 8; j++) {
      p[j] = __expf(v[j] - m);
      s += p[j];
    }
  }
#pragma unroll
  for (int off = 1; off < 64; off <<= 1) s += __shfl_xor(s, off);
  if (lane == 0) reds[wave] = s;
  __syncthreads();  // also fences: all global reads done before writes below
  const float inv = 1.0f / (reds[0] + reds[1] + reds[2] + reds[3]);
  if (act) {
    bf16x8 o;
#pragma unroll
    for (int j = 0; j < 8; j++) o[j] = (__bf16)(p[j] * inv);
    *(bf16x8*)(Prow + base) = o;
  }
}

// ---------------------------------------------------------------------------
extern "C" void kernel_launch(void* const* d_in, const int* in_sizes, int n_in,
                              void* d_out, int out_size, void* d_ws,
                              size_t ws_size, hipStream_t stream) {
  const float* x = (const float*)d_in[0];
  const float* Wq = (const float*)d_in[1];
  const float* bq = (const float*)d_in[2];
  const float* Wk = (const float*)d_in[3];
  const float* bk = (const float*)d_in[4];
  const float* Wv = (const float*)d_in[5];
  const float* bv = (const float*)d_in[6];
  const float* Wo = (const float*)d_in[7];
  const float* bo = (const float*)d_in[8];

  char* ws = (char*)d_ws;
  const size_t MB = 1u << 20;
  const size_t TC = (size_t)T_SEQ * D_MOD;   // 2M elems / batch
  const size_t TT = (size_t)T_SEQ * T_SEQ;   // 4M elems / batch
  __bf16* xb  = (__bf16*)(ws);               // [0,16) MB
  __bf16* Wqt = (__bf16*)(ws + 16 * MB);
  __bf16* Wkt = (__bf16*)(ws + 18 * MB);
  __bf16* Wvt = (__bf16*)(ws + 20 * MB);
  __bf16* Wot = (__bf16*)(ws + 22 * MB);
  __bf16* Qb  = (__bf16*)(ws + 24 * MB);     // [24,40)
  __bf16* Kb  = (__bf16*)(ws + 40 * MB);     // [40,56)
  __bf16* Vb  = (__bf16*)(ws + 56 * MB);     // [56,72)
  __bf16* Vtb = (__bf16*)(ws);               // alias xb (dead after projs)

  // 1) x -> bf16
  cvt_bf16_kernel<<<4096, 256, 0, stream>>>(x, xb, 8192 * D_MOD / 8);
  // 2) weight transposes (fp32 -> bf16, N x K)
  dim3 tb(32, 8);
  transpose_cvt_kernel<<<dim3(32, 32), tb, 0, stream>>>(Wq, Wqt);
  transpose_cvt_kernel<<<dim3(32, 32), tb, 0, stream>>>(Wk, Wkt);
  transpose_cvt_kernel<<<dim3(32, 32), tb, 0, stream>>>(Wv, Wvt);
  transpose_cvt_kernel<<<dim3(32, 32), tb, 0, stream>>>(Wo, Wot);
  // 3) QKV projections (M=8192, N=1024, K=1024)
  dim3 gg(64, 8, 1);
  gemm_kernel<0><<<gg, 256, 0, stream>>>(xb, Wqt, bq, Qb, D_MOD, D_MOD, D_MOD,
                                         D_MOD, 0, 0, 0);
  gemm_kernel<0><<<gg, 256, 0, stream>>>(xb, Wkt, bk, Kb, D_MOD, D_MOD, D_MOD,
                                         D_MOD, 0, 0, 0);
  gemm_kernel<0><<<gg, 256, 0, stream>>>(xb, Wvt, bv, Vb, D_MOD, D_MOD, D_MOD,
                                         D_MOD, 0, 0, 0);
  // 4) V -> V^T per batch (xb dead -> Vt aliases it)
  transpose_v_kernel<<<dim3(64, 32, 4), tb, 0, stream>>>(Vb, Vtb);

  const bool batched = ws_size >= 137 * MB;
  if (batched) {
    float* S = (float*)(ws + 72 * MB);       // [72,136) fp32, 4 batches
    __bf16* AO = Vb;                         // alias V (dead after transpose)
    // 5) S = Q K^T * scale, causal-masked (lower-tri blocks only)
    gemm_kernel<3><<<dim3(16, 16, 4), 256, 0, stream>>>(
        Qb, Kb, nullptr, S, D_MOD, D_MOD, T_SEQ, D_MOD, TC, TC, TT * 4);
    // 6) row softmax, P bf16 in-place (row stride 4096 bf16)
    softmax_kernel<<<dim3(T_SEQ, 4), 256, 0, stream>>>(S, TT);
    // 7) O = P V  (A = P, lda=4096; Bt = Vt, ldb=2048; triangular K)
    gemm_kernel<2><<<dim3(16, 8, 4), 256, 0, stream>>>(
        (const __bf16*)S, Vtb, nullptr, AO, 2 * T_SEQ, T_SEQ, D_MOD, 0,
        (size_t)T_SEQ * 2 * T_SEQ, (size_t)D_MOD * T_SEQ, TC * 2);
    // 8) out projection (fp32 out)
    gemm_kernel<1><<<gg, 256, 0, stream>>>(AO, Wot, bo, d_out, D_MOD, D_MOD,
                                           D_MOD, D_MOD, 0, 0, 0);
  } else {
    // fallback: per-batch S in the dead V slot (fits in 72MB proven ws)
    float* S = (float*)(ws + 56 * MB);       // 16MB, reused per batch
    __bf16* AO = Qb;                         // overwrite Q per batch
    for (int b = 0; b < 4; ++b) {
      gemm_kernel<3><<<dim3(16, 16, 1), 256, 0, stream>>>(
          Qb + b * TC, Kb + b * TC, nullptr, S, D_MOD, D_MOD, T_SEQ, D_MOD, 0,
          0, 0);
      softmax_kernel<<<dim3(T_SEQ, 1), 256, 0, stream>>>(S, 0);
      gemm_kernel<2><<<dim3(16, 8, 1), 256, 0, stream>>>(
          (const __bf16*)S, Vtb + b * TC, nullptr, AO + b * TC, 2 * T_SEQ,
          T_SEQ, D_MOD, 0, 0, 0, 0);
    }
    gemm_kernel<1><<<gg, 256, 0, stream>>>(AO, Wot, bo, d_out, D_MOD, D_MOD,
                                           D_MOD, D_MOD, 0, 0, 0);
  }
}

// Round 4
// 233.830 us; speedup vs baseline: 2.1819x; 1.0724x over previous
//
#include <hip/hip_runtime.h>
#include <hip/hip_bf16.h>
#include <stdint.h>

// ---------------------------------------------------------------------------
// MultiHeadAttention (no head split): out = softmax_causal((xWq)(xWk)^T/32)(xWv) Wo
// B=4, T=2048, C=1024, fp32 in/out, bf16 MFMA compute.
// Pipeline: fused QKV 8-phase 256^2 GEMM -> causal QK^T GEMM (fp32 S)
//           -> row softmax (P bf16 in-place) -> PV GEMM (tri-K) -> out proj.
// Round 4 = identical resubmit of round 3 (container died in infra push;
// kernel audit found no hang mechanism: uniform barriers, sound vmcnt
// bookkeeping, safe LDS buffer tenancy).
// ---------------------------------------------------------------------------

typedef __attribute__((ext_vector_type(8))) __bf16 bf16x8;
typedef __attribute__((ext_vector_type(4))) float f32x4;

#define MFMA16(A, B, C) __builtin_amdgcn_mfma_f32_16x16x32_bf16(A, B, C, 0, 0, 0)
#define BAR() asm volatile("s_barrier" ::: "memory")

#define T_SEQ 2048
#define D_MOD 1024

static __device__ __forceinline__ void gload_lds16(const void* g, void* l) {
  __builtin_amdgcn_global_load_lds(
      (const __attribute__((address_space(1))) void*)g,
      (__attribute__((address_space(3))) void*)l, 16, 0, 0);
}

// ------------------------- elementwise fp32 -> bf16 ------------------------
__global__ void cvt_bf16_kernel(const float* __restrict__ in,
                                __bf16* __restrict__ out, int n8) {
  int i = blockIdx.x * blockDim.x + threadIdx.x;
  if (i < n8) {
    const float4* p = (const float4*)(in + (size_t)i * 8);
    float4 a = p[0], b = p[1];
    bf16x8 o;
    o[0] = (__bf16)a.x; o[1] = (__bf16)a.y; o[2] = (__bf16)a.z; o[3] = (__bf16)a.w;
    o[4] = (__bf16)b.x; o[5] = (__bf16)b.y; o[6] = (__bf16)b.z; o[7] = (__bf16)b.w;
    *(bf16x8*)(out + (size_t)i * 8) = o;
  }
}

// -------------------- W (K x N fp32) -> Wt (N x K bf16) --------------------
__global__ void transpose_cvt_kernel(const float* __restrict__ W,
                                     __bf16* __restrict__ Wt) {
  __shared__ float tile[32][33];
  int tx = threadIdx.x, ty = threadIdx.y;
  int bx = blockIdx.x * 32, by = blockIdx.y * 32;
#pragma unroll
  for (int i = 0; i < 4; i++)
    tile[ty + 8 * i][tx] = W[(size_t)(by + ty + 8 * i) * D_MOD + bx + tx];
  __syncthreads();
#pragma unroll
  for (int i = 0; i < 4; i++)
    Wt[(size_t)(bx + ty + 8 * i) * D_MOD + by + tx] = (__bf16)tile[tx][ty + 8 * i];
}

// -------------- V [b][2048][1024] bf16 -> Vt [b][1024][2048] ---------------
__global__ void transpose_v_kernel(const __bf16* __restrict__ V,
                                   __bf16* __restrict__ Vt) {
  __shared__ __bf16 tile[32][33];
  int tx = threadIdx.x, ty = threadIdx.y;
  int b = blockIdx.z;
  int t0 = blockIdx.x * 32, d0 = blockIdx.y * 32;
  const __bf16* Vb = V + (size_t)b * T_SEQ * D_MOD;
  __bf16* Vtb = Vt + (size_t)b * D_MOD * T_SEQ;
#pragma unroll
  for (int i = 0; i < 4; i++)
    tile[ty + 8 * i][tx] = Vb[(size_t)(t0 + ty + 8 * i) * D_MOD + d0 + tx];
  __syncthreads();
#pragma unroll
  for (int i = 0; i < 4; i++)
    Vtb[(size_t)(d0 + ty + 8 * i) * T_SEQ + t0 + tx] = tile[tx][ty + 8 * i];
}

// ===================== fused QKV: 256^2 8-phase GEMM =======================
// C[8192][3072] = x[8192][1024] @ Wqkvt[3072][1024]^T + bias, routed to
// dense Q/K/V buffers by column segment. 512 thr = 8 waves (2Mx4N), BK=64,
// double-buffered 128KiB LDS, counted vmcnt (T4) + setprio (T5).
// LDS layout per 16KiB half-tile: [kk(2)][row(128)][col(32 bf16)] -> 64B row
// stride => MFMA frag ds_read_b128 is bank-conflict-free (8 dwords/bank).
// Staging: per-lane pre-permuted GLOBAL source, linear LDS dest (m173).

template <int MG, int NG>
static __device__ __forceinline__ void mfma_quad(f32x4 (&acc)[8][4],
                                                 const bf16x8 (&aR)[4][2],
                                                 const bf16x8 (&bR)[2][2]) {
#pragma unroll
  for (int i = 0; i < 4; i++)
#pragma unroll
    for (int n = 0; n < 2; n++)
#pragma unroll
      for (int kk = 0; kk < 2; kk++)
        acc[MG * 4 + i][NG * 2 + n] =
            MFMA16(aR[i][kk], bR[n][kk], acc[MG * 4 + i][NG * 2 + n]);
}

__global__ __launch_bounds__(512, 2) void gemm_qkv_kernel(
    const __bf16* __restrict__ A, const __bf16* __restrict__ Bt,
    const float* __restrict__ bq, const float* __restrict__ bk,
    const float* __restrict__ bv, __bf16* __restrict__ Qo,
    __bf16* __restrict__ Ko, __bf16* __restrict__ Vo) {
  constexpr int LD = 1024;
  constexpr int NT = LD / 64;  // 16 K-tiles
  __shared__ __align__(16) char lds[131072];
#define ABUF(p, h) (lds + ((p) * 2 + (h)) * 16384)
#define BBUF(p, h) (lds + 65536 + ((p) * 2 + (h)) * 16384)

  const int tid = threadIdx.x;
  const int w = tid >> 6, l = tid & 63;
  const int wr = w >> 2, wc = w & 3;  // 2 x 4 wave grid
  // XCD-aware bijective swizzle (gridDim.x = 384, % 8 == 0)
  const int cpx = gridDim.x >> 3;
  const int swz = ((int)blockIdx.x & 7) * cpx + ((int)blockIdx.x >> 3);
  const int nbn = 12;  // 3072/256
  const int bm = (swz / nbn) * 256;
  const int bn = (swz % nbn) * 256;

  const int srow = l >> 2;          // staging row within 16-row stripe
  const int scol = (l & 3) * 8;     // staging col elems
  const int rlo = l & 15;           // frag row
  const int cb16 = (l >> 4) * 16;   // frag 16B chunk within 64B LDS row

#define STAGE_A(t, h)                                                       \
  {                                                                         \
    char* lb = ABUF((t) & 1, h) + w * 1024;                                 \
    const __bf16* g = A + (size_t)(bm + (h) * 128 + w * 16 + srow) * LD +   \
                      (t) * 64 + scol;                                      \
    gload_lds16(g, lb);                                                     \
    gload_lds16(g + 32, lb + 8192);                                         \
  }
#define STAGE_B(t, h)                                                       \
  {                                                                         \
    char* lb = BBUF((t) & 1, h) + w * 1024;                                 \
    const __bf16* g = Bt + (size_t)(bn + (h) * 128 + w * 16 + srow) * LD +  \
                      (t) * 64 + scol;                                      \
    gload_lds16(g, lb);                                                     \
    gload_lds16(g + 32, lb + 8192);                                         \
  }
#define LDA_FRAG(p, g, i, kk)                                    \
  (*(const bf16x8*)(ABUF(p, wr) + (kk) * 8192 +                  \
                    ((g) * 64 + (i) * 16 + rlo) * 64 + cb16))
#define LDB_FRAG(p, g, n, kk)                                    \
  (*(const bf16x8*)(BBUF(p, (wc >> 1)) + (kk) * 8192 +           \
                    ((wc & 1) * 64 + (g) * 32 + (n) * 16 + rlo) * 64 + cb16))

  f32x4 acc[8][4] = {};
  // prologue: A(0) both halves, B(0) both halves, A(1) both halves
  STAGE_A(0, 0); STAGE_A(0, 1);
  STAGE_B(0, 0); STAGE_B(0, 1);
  STAGE_A(1, 0); STAGE_A(1, 1);
  asm volatile("s_waitcnt vmcnt(4)" ::: "memory");  // A(0),B(0) landed
  BAR();

  for (int t = 0; t < NT; ++t) {
    const int p = t & 1;
    bf16x8 a[4][2], b[2][2];
    // ---- phase a: read A-g0 + B-g0; stage B-h0(t+1); MFMA Q(0,0) ----
#pragma unroll
    for (int i = 0; i < 4; i++) {
      a[i][0] = LDA_FRAG(p, 0, i, 0);
      a[i][1] = LDA_FRAG(p, 0, i, 1);
    }
#pragma unroll
    for (int n = 0; n < 2; n++) {
      b[n][0] = LDB_FRAG(p, 0, n, 0);
      b[n][1] = LDB_FRAG(p, 0, n, 1);
    }
    if (t + 1 < NT) STAGE_B(t + 1, 0);
    BAR();
    __builtin_amdgcn_s_setprio(1);
    mfma_quad<0, 0>(acc, a, b);
    __builtin_amdgcn_s_setprio(0);
    BAR();
    // ---- phase b: read B-g1; stage B-h1(t+1); MFMA Q(0,1) ----
    bf16x8 b2[2][2];
#pragma unroll
    for (int n = 0; n < 2; n++) {
      b2[n][0] = LDB_FRAG(p, 1, n, 0);
      b2[n][1] = LDB_FRAG(p, 1, n, 1);
    }
    if (t + 1 < NT) STAGE_B(t + 1, 1);
    BAR();
    __builtin_amdgcn_s_setprio(1);
    mfma_quad<0, 1>(acc, a, b2);
    __builtin_amdgcn_s_setprio(0);
    BAR();
    // ---- phase c: read A-g1; MFMA Q(1,1) ----
#pragma unroll
    for (int i = 0; i < 4; i++) {
      a[i][0] = LDA_FRAG(p, 1, i, 0);
      a[i][1] = LDA_FRAG(p, 1, i, 1);
    }
    BAR();
    __builtin_amdgcn_s_setprio(1);
    mfma_quad<1, 1>(acc, a, b2);
    __builtin_amdgcn_s_setprio(0);
    BAR();
    // ---- phase d: re-read B-g0; stage A(t+2) both halves; MFMA Q(1,0);
    //      counted vmcnt so tile t+1 is fully landed, A(t+2) in flight ----
#pragma unroll
    for (int n = 0; n < 2; n++) {
      b[n][0] = LDB_FRAG(p, 0, n, 0);
      b[n][1] = LDB_FRAG(p, 0, n, 1);
    }
    if (t + 2 < NT) {
      STAGE_A(t + 2, 0); STAGE_A(t + 2, 1);
      BAR();
      __builtin_amdgcn_s_setprio(1);
      mfma_quad<1, 0>(acc, a, b);
      __builtin_amdgcn_s_setprio(0);
      asm volatile("s_waitcnt vmcnt(4)" ::: "memory");
      BAR();
    } else {
      BAR();
      __builtin_amdgcn_s_setprio(1);
      mfma_quad<1, 0>(acc, a, b);
      __builtin_amdgcn_s_setprio(0);
      asm volatile("s_waitcnt vmcnt(0)" ::: "memory");
      BAR();
    }
  }

  // epilogue: route column segment to Q/K/V (tiles never straddle 1024-bdry)
  const float* bsel = (bn < 1024) ? bq : (bn < 2048) ? bk : bv;
  __bf16* osel = (bn < 1024) ? Qo : (bn < 2048) ? Ko : Vo;
  const int bnl = bn & 1023;
#pragma unroll
  for (int n4 = 0; n4 < 4; n4++) {
    int col = bnl + wc * 64 + n4 * 16 + rlo;
    float bvv = bsel[col];
#pragma unroll
    for (int mi = 0; mi < 8; mi++) {
      int row = bm + wr * 128 + mi * 16 + (l >> 4) * 4;
#pragma unroll
      for (int r = 0; r < 4; r++)
        osel[(size_t)(row + r) * LD + col] = (__bf16)(acc[mi][n4][r] + bvv);
    }
  }
#undef ABUF
#undef BBUF
#undef STAGE_A
#undef STAGE_B
#undef LDA_FRAG
#undef LDB_FRAG
}

// --------------------------- m97 128^2 GEMM --------------------------------
// MODE: 1 = out-proj (bias, f32 out), 2 = PV (bf16 out, K=(bx+1)*128),
//       3 = QK (scale+causal mask, f32 out, skip upper-tri blocks)
template <int MODE>
__global__ __launch_bounds__(256) void gemm_kernel(
    const __bf16* __restrict__ A, const __bf16* __restrict__ Bt,
    const float* __restrict__ bias, void* __restrict__ Cp, int lda, int ldb,
    int ldc, int Kparam, size_t bsA, size_t bsB, size_t bsCbytes) {
  if (MODE == 3 && blockIdx.y > blockIdx.x) return;  // fully-masked block
  constexpr int BK = 32;
  __shared__ __align__(16) __bf16 lA[2][128 * BK];
  __shared__ __align__(16) __bf16 lB[2][128 * BK];
  const int z = blockIdx.z;
  A += (size_t)z * bsA;
  Bt += (size_t)z * bsB;
  char* Cbase = (char*)Cp + (size_t)z * bsCbytes;
  const int K = (MODE == 2) ? (int)(blockIdx.x + 1) * 128 : Kparam;

  const int tid = threadIdx.x;
  const int wave = tid >> 6, lane = tid & 63;
  const int bm = blockIdx.x * 128, bn = blockIdx.y * 128;
  const int wr = wave >> 1, wc = wave & 1;
  f32x4 acc[4][4] = {};

  const int srow = lane >> 2;
  const int skc = (lane & 3) * 8;

  const int NT = K / BK;
  {
#pragma unroll
    for (int i = 0; i < 2; i++) {
      int c = wave * 2 + i;
      gload_lds16(A + (size_t)(bm + c * 16 + srow) * lda + skc, &lA[0][c * 512]);
      gload_lds16(Bt + (size_t)(bn + c * 16 + srow) * ldb + skc, &lB[0][c * 512]);
    }
  }
  __syncthreads();

  const int arow = wr * 64 + (lane & 15);
  const int brow = wc * 64 + (lane & 15);
  const int kb = (lane >> 4) * 8;
  int cur = 0;
  for (int kt = 0; kt < NT; ++kt) {
    if (kt + 1 < NT) {
      const int k0 = (kt + 1) * BK;
#pragma unroll
      for (int i = 0; i < 2; i++) {
        int c = wave * 2 + i;
        gload_lds16(A + (size_t)(bm + c * 16 + srow) * lda + k0 + skc,
                    &lA[cur ^ 1][c * 512]);
        gload_lds16(Bt + (size_t)(bn + c * 16 + srow) * ldb + k0 + skc,
                    &lB[cur ^ 1][c * 512]);
      }
    }
    bf16x8 af[4], bfg[4];
#pragma unroll
    for (int i = 0; i < 4; i++)
      af[i] = *(const bf16x8*)&lA[cur][(arow + 16 * i) * BK + kb];
#pragma unroll
    for (int j = 0; j < 4; j++)
      bfg[j] = *(const bf16x8*)&lB[cur][(brow + 16 * j) * BK + kb];
#pragma unroll
    for (int i = 0; i < 4; i++)
#pragma unroll
      for (int j = 0; j < 4; j++)
        acc[i][j] = MFMA16(af[i], bfg[j], acc[i][j]);
    __syncthreads();
    cur ^= 1;
  }

#pragma unroll
  for (int j = 0; j < 4; j++) {
    int col = bn + wc * 64 + j * 16 + (lane & 15);
    float bv = (MODE == 1) ? bias[col] : 0.0f;
#pragma unroll
    for (int i = 0; i < 4; i++) {
      int rbase = bm + wr * 64 + i * 16 + (lane >> 4) * 4;
#pragma unroll
      for (int r = 0; r < 4; r++) {
        int row = rbase + r;
        float v = acc[i][j][r];
        if (MODE == 3) {
          v *= 0.03125f;  // 1/sqrt(1024)
          if (col > row) v = -1e30f;
          ((float*)Cbase)[(size_t)row * ldc + col] = v;
        } else if (MODE == 1) {
          ((float*)Cbase)[(size_t)row * ldc + col] = v + bv;
        } else {
          ((__bf16*)Cbase)[(size_t)row * ldc + col] = (__bf16)v;
        }
      }
    }
  }
}

// ----------------------- row softmax, P bf16 in-place ----------------------
__global__ __launch_bounds__(256) void softmax_kernel(float* __restrict__ S,
                                                      size_t bstride) {
  const int t = blockIdx.x, b = blockIdx.y;
  float* Srow = S + (size_t)b * bstride + (size_t)t * T_SEQ;
  __bf16* Prow = (__bf16*)Srow;
  const int L = ((t + 1) + 127) & ~127;
  const int tid = threadIdx.x;
  const int base = tid * 8;
  const bool act = base < L;
  float v[8];
  float m = -1e30f;
  if (act) {
    float4 a = *(const float4*)(Srow + base);
    float4 c = *(const float4*)(Srow + base + 4);
    v[0] = a.x; v[1] = a.y; v[2] = a.z; v[3] = a.w;
    v[4] = c.x; v[5] = c.y; v[6] = c.z; v[7] = c.w;
#pragma unroll
    for (int j = 0; j < 8; j++) m = fmaxf(m, v[j]);
  }
#pragma unroll
  for (int off = 1; off < 64; off <<= 1) m = fmaxf(m, __shfl_xor(m, off));
  __shared__ float redm[4], reds[4];
  const int wave = tid >> 6, lane = tid & 63;
  if (lane == 0) redm[wave] = m;
  __syncthreads();
  m = fmaxf(fmaxf(redm[0], redm[1]), fmaxf(redm[2], redm[3]));
  float p[8];
  float s = 0.f;
  if (act) {
#pragma unroll
    for (int j = 0; j < 8; j++) {
      p[j] = __expf(v[j] - m);
      s += p[j];
    }
  }
#pragma unroll
  for (int off = 1; off < 64; off <<= 1) s += __shfl_xor(s, off);
  if (lane == 0) reds[wave] = s;
  __syncthreads();  // fences: reads done before in-place bf16 writes
  const float inv = 1.0f / (reds[0] + reds[1] + reds[2] + reds[3]);
  if (act) {
    bf16x8 o;
#pragma unroll
    for (int j = 0; j < 8; j++) o[j] = (__bf16)(p[j] * inv);
    *(bf16x8*)(Prow + base) = o;
  }
}

// ---------------------------------------------------------------------------
extern "C" void kernel_launch(void* const* d_in, const int* in_sizes, int n_in,
                              void* d_out, int out_size, void* d_ws,
                              size_t ws_size, hipStream_t stream) {
  const float* x = (const float*)d_in[0];
  const float* Wq = (const float*)d_in[1];
  const float* bq = (const float*)d_in[2];
  const float* Wk = (const float*)d_in[3];
  const float* bk = (const float*)d_in[4];
  const float* Wv = (const float*)d_in[5];
  const float* bv = (const float*)d_in[6];
  const float* Wo = (const float*)d_in[7];
  const float* bo = (const float*)d_in[8];

  char* ws = (char*)d_ws;
  const size_t MB = 1u << 20;
  const size_t TC = (size_t)T_SEQ * D_MOD;  // 2M elems / batch
  const size_t TT = (size_t)T_SEQ * T_SEQ;  // 4M elems / batch
  __bf16* xb    = (__bf16*)(ws);            // [0,16) MB ; later Vt
  __bf16* Wqkvt = (__bf16*)(ws + 16 * MB);  // [16,22)  3072x1024
  __bf16* Wot   = (__bf16*)(ws + 22 * MB);  // [22,24)
  __bf16* Qb    = (__bf16*)(ws + 24 * MB);  // [24,40)
  __bf16* Kb    = (__bf16*)(ws + 40 * MB);  // [40,56)
  __bf16* Vb    = (__bf16*)(ws + 56 * MB);  // [56,72) ; later AO (batched)
  __bf16* Vtb   = (__bf16*)(ws);            // alias xb (dead after QKV GEMM)

  // 1) x -> bf16
  cvt_bf16_kernel<<<4096, 256, 0, stream>>>(x, xb, 8192 * D_MOD / 8);
  // 2) weight transposes into fused Wqkvt rows [0,1024)=Wq^T etc.
  dim3 tb(32, 8);
  transpose_cvt_kernel<<<dim3(32, 32), tb, 0, stream>>>(Wq, Wqkvt);
  transpose_cvt_kernel<<<dim3(32, 32), tb, 0, stream>>>(Wk, Wqkvt + 1024 * 1024);
  transpose_cvt_kernel<<<dim3(32, 32), tb, 0, stream>>>(Wv, Wqkvt + 2048 * 1024);
  transpose_cvt_kernel<<<dim3(32, 32), tb, 0, stream>>>(Wo, Wot);
  // 3) fused QKV projection, 256^2 8-phase (384 WGs)
  gemm_qkv_kernel<<<384, 512, 0, stream>>>(xb, Wqkvt, bq, bk, bv, Qb, Kb, Vb);
  // 4) V -> V^T per batch (xb dead -> Vt aliases it)
  transpose_v_kernel<<<dim3(64, 32, 4), tb, 0, stream>>>(Vb, Vtb);

  const bool batched = ws_size >= 137 * MB;
  if (batched) {
    float* S = (float*)(ws + 72 * MB);  // [72,136) fp32, 4 batches
    __bf16* AO = Vb;                    // alias V (dead after transpose)
    gemm_kernel<3><<<dim3(16, 16, 4), 256, 0, stream>>>(
        Qb, Kb, nullptr, S, D_MOD, D_MOD, T_SEQ, D_MOD, TC, TC, TT * 4);
    softmax_kernel<<<dim3(T_SEQ, 4), 256, 0, stream>>>(S, TT);
    gemm_kernel<2><<<dim3(16, 8, 4), 256, 0, stream>>>(
        (const __bf16*)S, Vtb, nullptr, AO, 2 * T_SEQ, T_SEQ, D_MOD, 0,
        (size_t)T_SEQ * 2 * T_SEQ, (size_t)D_MOD * T_SEQ, TC * 2);
    gemm_kernel<1><<<dim3(64, 8, 1), 256, 0, stream>>>(
        AO, Wot, bo, d_out, D_MOD, D_MOD, D_MOD, D_MOD, 0, 0, 0);
  } else {
    // per-batch fallback within 72MB: S reuses Vb slot, AO overwrites Qb
    float* S = (float*)(ws + 56 * MB);
    __bf16* AO = Qb;
    for (int b = 0; b < 4; ++b) {
      gemm_kernel<3><<<dim3(16, 16, 1), 256, 0, stream>>>(
          Qb + b * TC, Kb + b * TC, nullptr, S, D_MOD, D_MOD, T_SEQ, D_MOD, 0,
          0, 0);
      softmax_kernel<<<dim3(T_SEQ, 1), 256, 0, stream>>>(S, 0);
      gemm_kernel<2><<<dim3(16, 8, 1), 256, 0, stream>>>(
          (const __bf16*)S, Vtb + b * TC, nullptr, AO + b * TC, 2 * T_SEQ,
          T_SEQ, D_MOD, 0, 0, 0, 0);
    }
    gemm_kernel<1><<<dim3(64, 8, 1), 256, 0, stream>>>(
        AO, Wot, bo, d_out, D_MOD, D_MOD, D_MOD, D_MOD, 0, 0, 0);
  }
}

// Round 5
// 201.011 us; speedup vs baseline: 2.5381x; 1.1633x over previous
//
#include <hip/hip_runtime.h>
#include <hip/hip_bf16.h>
#include <stdint.h>

// ---------------------------------------------------------------------------
// MultiHeadAttention (no head split): out = softmax_causal((xWq)(xWk)^T/32)(xWv) Wo
// B=4, T=2048, C=1024, fp32 in/out, bf16 MFMA compute.
// All GEMMs: unified 128x256 8-phase template, BK=64, 8 waves, triple-buffer
// LDS (144KiB), bank-conflict swizzle (c' = c ^ ((row>>1)&3)), counted vmcnt.
// ---------------------------------------------------------------------------

typedef __attribute__((ext_vector_type(8))) __bf16 bf16x8;
typedef __attribute__((ext_vector_type(4))) float f32x4;

#define MFMA16(A, B, C) __builtin_amdgcn_mfma_f32_16x16x32_bf16(A, B, C, 0, 0, 0)
#define BAR() asm volatile("s_barrier" ::: "memory")

#define T_SEQ 2048
#define D_MOD 1024

static __device__ __forceinline__ void gload_lds16(const void* g, void* l) {
  __builtin_amdgcn_global_load_lds(
      (const __attribute__((address_space(1))) void*)g,
      (__attribute__((address_space(3))) void*)l, 16, 0, 0);
}

// ------------------------- elementwise fp32 -> bf16 ------------------------
__global__ void cvt_bf16_kernel(const float* __restrict__ in,
                                __bf16* __restrict__ out, int n8) {
  int i = blockIdx.x * blockDim.x + threadIdx.x;
  if (i < n8) {
    const float4* p = (const float4*)(in + (size_t)i * 8);
    float4 a = p[0], b = p[1];
    bf16x8 o;
    o[0] = (__bf16)a.x; o[1] = (__bf16)a.y; o[2] = (__bf16)a.z; o[3] = (__bf16)a.w;
    o[4] = (__bf16)b.x; o[5] = (__bf16)b.y; o[6] = (__bf16)b.z; o[7] = (__bf16)b.w;
    *(bf16x8*)(out + (size_t)i * 8) = o;
  }
}

// -------------------- W (K x N fp32) -> Wt (N x K bf16) --------------------
__global__ void transpose_cvt_kernel(const float* __restrict__ W,
                                     __bf16* __restrict__ Wt) {
  __shared__ float tile[32][33];
  int tx = threadIdx.x, ty = threadIdx.y;
  int bx = blockIdx.x * 32, by = blockIdx.y * 32;
#pragma unroll
  for (int i = 0; i < 4; i++)
    tile[ty + 8 * i][tx] = W[(size_t)(by + ty + 8 * i) * D_MOD + bx + tx];
  __syncthreads();
#pragma unroll
  for (int i = 0; i < 4; i++)
    Wt[(size_t)(bx + ty + 8 * i) * D_MOD + by + tx] = (__bf16)tile[tx][ty + 8 * i];
}

// -------------- V [b][2048][1024] bf16 -> Vt [b][1024][2048] ---------------
__global__ void transpose_v_kernel(const __bf16* __restrict__ V,
                                   __bf16* __restrict__ Vt) {
  __shared__ __bf16 tile[32][33];
  int tx = threadIdx.x, ty = threadIdx.y;
  int b = blockIdx.z;
  int t0 = blockIdx.x * 32, d0 = blockIdx.y * 32;
  const __bf16* Vb = V + (size_t)b * T_SEQ * D_MOD;
  __bf16* Vtb = Vt + (size_t)b * D_MOD * T_SEQ;
#pragma unroll
  for (int i = 0; i < 4; i++)
    tile[ty + 8 * i][tx] = Vb[(size_t)(t0 + ty + 8 * i) * D_MOD + d0 + tx];
  __syncthreads();
#pragma unroll
  for (int i = 0; i < 4; i++)
    Vtb[(size_t)(d0 + ty + 8 * i) * T_SEQ + t0 + tx] = tile[tx][ty + 8 * i];
}

// ====================== unified 128x256 8-phase GEMM =======================
// C = A @ Bt^T (+bias).  A: Mx K bf16 (lda).  Bt: N x K bf16 (ldb).
// BM=128, BN=256, BK=64.  8 waves (2M x 4N), wave tile 64x64, acc[4][4].
// LDS: A 3x16KB + B 3x32KB = 144KB triple buffer.
//   A buf: [kk(2)@8192][row(128)@64B]; B buf: [kk(2)@16384][row(256)@64B];
//   swizzle: physical 16B-chunk c' = c ^ ((row>>1)&3)  (bank-conflict-free
//   quarter-wave reads); staging uses linear LDS dest + pre-swizzled global
//   source column (cswz), which composes to the same mapping.
// Schedule per K-tile t (2 phases, 2 barriers each):
//   phA: ds_read A(t)[8] + B(t)n01[4]; stage A(t+2); BAR; MFMA 16; BAR
//   phB: ds_read B(t)n23[4]; stage B(t+2); BAR; MFMA 16; vmcnt(6|0); BAR
// Triple buffer => stage target (t+2)%3 == (t-1)%3, read-complete by barrier
// discipline. vmcnt(6): exactly tile t's 6 stages left in flight.
// MODE: 0 = QKV (bf16 out routed by col segment, bias b0/b1/b2)
//       1 = out-proj (f32 out ldc=1024, bias b0)
//       2 = PV (bf16 out, no bias, K=(i+1)*128 triangular)
//       3 = QK (f32 out ldc=2048, scale+causal mask, skip upper-tri)
template <int MODE>
__global__ __launch_bounds__(512, 2) void ugemm_kernel(
    const __bf16* __restrict__ A, const __bf16* __restrict__ Bt,
    const float* __restrict__ b0, const float* __restrict__ b1,
    const float* __restrict__ b2, void* __restrict__ o0,
    void* __restrict__ o1, void* __restrict__ o2, int lda, int ldb,
    size_t bsA, size_t bsB, size_t bsC) {
  __shared__ __align__(16) char lds[147456];
#define ABUF(p3) (lds + (p3) * 16384)
#define BBUF(p3) (lds + 49152 + (p3) * 32768)

  const int tid = threadIdx.x;
  const int w = tid >> 6, l = tid & 63;
  const int wr = w >> 2, wc = w & 3;  // 2M x 4N wave grid
  const int z = blockIdx.z;

  int bm, bn, NT;
  if (MODE == 0) {
    const int cpx = gridDim.x >> 3;  // XCD bijective swizzle (768 % 8 == 0)
    const int swz = ((int)blockIdx.x & 7) * cpx + ((int)blockIdx.x >> 3);
    bm = (swz / 12) * 128; bn = (swz % 12) * 256; NT = 16;
  } else if (MODE == 1) {
    const int cpx = gridDim.x >> 3;  // 256 % 8 == 0
    const int swz = ((int)blockIdx.x & 7) * cpx + ((int)blockIdx.x >> 3);
    bm = (swz >> 2) * 128; bn = (swz & 3) * 256; NT = 16;
  } else if (MODE == 2) {
    const int i = (int)blockIdx.x >> 2;
    bm = i * 128; bn = ((int)blockIdx.x & 3) * 256; NT = (i + 1) * 2;
  } else {
    const int i = blockIdx.x, j = blockIdx.y;
    if (2 * j > i) return;  // fully-masked tile
    bm = i * 128; bn = j * 256; NT = 16;
  }
  A += (size_t)z * bsA;
  Bt += (size_t)z * bsB;

  const int grow = w * 16 + (l >> 2);              // staged row (0..127)
  const int cswz = (l & 3) ^ ((l >> 3) & 3);       // pre-swizzled src chunk
  const int rlo = l & 15;                          // frag row within 16
  const int xsw = (((l >> 4) ^ ((l >> 1) & 3)) << 4);  // swizzled read chunk

#define STAGE_A(t, p3)                                                       \
  {                                                                          \
    const __bf16* g = A + (size_t)(bm + grow) * lda + (t) * 64 + cswz * 8;   \
    char* d = ABUF(p3) + w * 1024 + l * 16;                                  \
    gload_lds16(g, d);                                                       \
    gload_lds16(g + 32, d + 8192);                                           \
  }
#define STAGE_B(t, p3)                                                       \
  {                                                                          \
    const __bf16* g = Bt + (size_t)(bn + grow) * ldb + (t) * 64 + cswz * 8;  \
    char* d = BBUF(p3) + w * 1024 + l * 16;                                  \
    gload_lds16(g, d);                                                       \
    gload_lds16(g + 32, d + 16384);                                          \
    const __bf16* g2 = g + (size_t)128 * ldb;                                \
    gload_lds16(g2, d + 8192);                                               \
    gload_lds16(g2 + 32, d + 8192 + 16384);                                  \
  }
#define LDA_FRAG(p3, i, kk)                                       \
  (*(const bf16x8*)(ABUF(p3) + (kk) * 8192 +                      \
                    (wr * 64 + (i) * 16 + rlo) * 64 + xsw))
#define LDB_FRAG(p3, n, kk)                                       \
  (*(const bf16x8*)(BBUF(p3) + (kk) * 16384 +                     \
                    (wc * 64 + (n) * 16 + rlo) * 64 + xsw))

  f32x4 acc[4][4] = {};
  // prologue: tiles 0 and 1 into buffers 0 and 1
  STAGE_A(0, 0); STAGE_B(0, 0);
  STAGE_A(1, 1); STAGE_B(1, 1);
  asm volatile("s_waitcnt vmcnt(6)" ::: "memory");  // tile 0's 6 landed
  BAR();

  int p = 0, pn2 = 2;  // t%3 and (t+2)%3
  for (int t = 0; t < NT; ++t) {
    bf16x8 af[4][2], bf01[2][2], bf23[2][2];
    // ---- phase A: A frags + B n01; stage A(t+2); MFMA n01 ----
#pragma unroll
    for (int i = 0; i < 4; i++) {
      af[i][0] = LDA_FRAG(p, i, 0);
      af[i][1] = LDA_FRAG(p, i, 1);
    }
#pragma unroll
    for (int n = 0; n < 2; n++) {
      bf01[n][0] = LDB_FRAG(p, n, 0);
      bf01[n][1] = LDB_FRAG(p, n, 1);
    }
    if (t + 2 < NT) STAGE_A(t + 2, pn2);
    BAR();
    __builtin_amdgcn_s_setprio(1);
#pragma unroll
    for (int i = 0; i < 4; i++)
#pragma unroll
      for (int n = 0; n < 2; n++) {
        acc[i][n] = MFMA16(af[i][0], bf01[n][0], acc[i][n]);
        acc[i][n] = MFMA16(af[i][1], bf01[n][1], acc[i][n]);
      }
    __builtin_amdgcn_s_setprio(0);
    BAR();
    // ---- phase B: B n23; stage B(t+2); MFMA n23; counted vmcnt ----
#pragma unroll
    for (int n = 0; n < 2; n++) {
      bf23[n][0] = LDB_FRAG(p, n + 2, 0);
      bf23[n][1] = LDB_FRAG(p, n + 2, 1);
    }
    if (t + 2 < NT) STAGE_B(t + 2, pn2);
    BAR();
    __builtin_amdgcn_s_setprio(1);
#pragma unroll
    for (int i = 0; i < 4; i++)
#pragma unroll
      for (int n = 0; n < 2; n++) {
        acc[i][n + 2] = MFMA16(af[i][0], bf23[n][0], acc[i][n + 2]);
        acc[i][n + 2] = MFMA16(af[i][1], bf23[n][1], acc[i][n + 2]);
      }
    __builtin_amdgcn_s_setprio(0);
    if (t + 2 < NT) {
      asm volatile("s_waitcnt vmcnt(6)" ::: "memory");
    } else {
      asm volatile("s_waitcnt vmcnt(0)" ::: "memory");
    }
    BAR();
    p = (p + 1 == 3) ? 0 : p + 1;
    pn2 = (pn2 + 1 == 3) ? 0 : pn2 + 1;
  }

  // ---- epilogue: D frag row=(l>>4)*4+r, col=rlo ----
  if (MODE == 0) {
    const int seg = bn >> 10;
    const float* bs = (seg == 0) ? b0 : (seg == 1) ? b1 : b2;
    __bf16* os = (__bf16*)((seg == 0) ? o0 : (seg == 1) ? o1 : o2);
    const int bnl = bn & 1023;
#pragma unroll
    for (int n = 0; n < 4; n++) {
      int col = bnl + wc * 64 + n * 16 + rlo;
      float bvv = bs[col];
#pragma unroll
      for (int m = 0; m < 4; m++) {
        int rowb = bm + wr * 64 + m * 16 + (l >> 4) * 4;
#pragma unroll
        for (int r = 0; r < 4; r++)
          os[(size_t)(rowb + r) * D_MOD + col] = (__bf16)(acc[m][n][r] + bvv);
      }
    }
  } else if (MODE == 1) {
    float* os = (float*)o0;
#pragma unroll
    for (int n = 0; n < 4; n++) {
      int col = bn + wc * 64 + n * 16 + rlo;
      float bvv = b0[col];
#pragma unroll
      for (int m = 0; m < 4; m++) {
        int rowb = bm + wr * 64 + m * 16 + (l >> 4) * 4;
#pragma unroll
        for (int r = 0; r < 4; r++)
          os[(size_t)(rowb + r) * D_MOD + col] = acc[m][n][r] + bvv;
      }
    }
  } else if (MODE == 2) {
    __bf16* os = (__bf16*)o0 + (size_t)z * bsC;
#pragma unroll
    for (int n = 0; n < 4; n++) {
      int col = bn + wc * 64 + n * 16 + rlo;
#pragma unroll
      for (int m = 0; m < 4; m++) {
        int rowb = bm + wr * 64 + m * 16 + (l >> 4) * 4;
#pragma unroll
        for (int r = 0; r < 4; r++)
          os[(size_t)(rowb + r) * D_MOD + col] = (__bf16)acc[m][n][r];
      }
    }
  } else {
    float* os = (float*)o0 + (size_t)z * bsC;
#pragma unroll
    for (int n = 0; n < 4; n++) {
      int col = bn + wc * 64 + n * 16 + rlo;
#pragma unroll
      for (int m = 0; m < 4; m++) {
        int rowb = bm + wr * 64 + m * 16 + (l >> 4) * 4;
#pragma unroll
        for (int r = 0; r < 4; r++) {
          int row = rowb + r;
          float v = acc[m][n][r] * 0.03125f;  // 1/sqrt(1024)
          if (col > row) v = -1e30f;
          os[(size_t)row * T_SEQ + col] = v;
        }
      }
    }
  }
#undef ABUF
#undef BBUF
#undef STAGE_A
#undef STAGE_B
#undef LDA_FRAG
#undef LDB_FRAG
}

// ----------------------- row softmax, P bf16 in-place ----------------------
__global__ __launch_bounds__(256) void softmax_kernel(float* __restrict__ S,
                                                      size_t bstride) {
  const int t = blockIdx.x, b = blockIdx.y;
  float* Srow = S + (size_t)b * bstride + (size_t)t * T_SEQ;
  __bf16* Prow = (__bf16*)Srow;
  const int L = ((t + 1) + 127) & ~127;
  const int tid = threadIdx.x;
  const int base = tid * 8;
  const bool act = base < L;
  float v[8];
  float m = -1e30f;
  if (act) {
    float4 a = *(const float4*)(Srow + base);
    float4 c = *(const float4*)(Srow + base + 4);
    v[0] = a.x; v[1] = a.y; v[2] = a.z; v[3] = a.w;
    v[4] = c.x; v[5] = c.y; v[6] = c.z; v[7] = c.w;
#pragma unroll
    for (int j = 0; j < 8; j++) m = fmaxf(m, v[j]);
  }
#pragma unroll
  for (int off = 1; off < 64; off <<= 1) m = fmaxf(m, __shfl_xor(m, off));
  __shared__ float redm[4], reds[4];
  const int wave = tid >> 6, lane = tid & 63;
  if (lane == 0) redm[wave] = m;
  __syncthreads();
  m = fmaxf(fmaxf(redm[0], redm[1]), fmaxf(redm[2], redm[3]));
  float p[8];
  float s = 0.f;
  if (act) {
#pragma unroll
    for (int j = 0; j < 8; j++) {
      p[j] = __expf(v[j] - m);
      s += p[j];
    }
  }
#pragma unroll
  for (int off = 1; off < 64; off <<= 1) s += __shfl_xor(s, off);
  if (lane == 0) reds[wave] = s;
  __syncthreads();  // fences: reads done before in-place bf16 writes
  const float inv = 1.0f / (reds[0] + reds[1] + reds[2] + reds[3]);
  if (act) {
    bf16x8 o;
#pragma unroll
    for (int j = 0; j < 8; j++) o[j] = (__bf16)(p[j] * inv);
    *(bf16x8*)(Prow + base) = o;
  }
}

// ---------------------------------------------------------------------------
extern "C" void kernel_launch(void* const* d_in, const int* in_sizes, int n_in,
                              void* d_out, int out_size, void* d_ws,
                              size_t ws_size, hipStream_t stream) {
  const float* x = (const float*)d_in[0];
  const float* Wq = (const float*)d_in[1];
  const float* bq = (const float*)d_in[2];
  const float* Wk = (const float*)d_in[3];
  const float* bk = (const float*)d_in[4];
  const float* Wv = (const float*)d_in[5];
  const float* bv = (const float*)d_in[6];
  const float* Wo = (const float*)d_in[7];
  const float* bo = (const float*)d_in[8];

  char* ws = (char*)d_ws;
  const size_t MB = 1u << 20;
  const size_t TC = (size_t)T_SEQ * D_MOD;  // 2M elems / batch
  const size_t TT = (size_t)T_SEQ * T_SEQ;  // 4M elems / batch
  __bf16* xb    = (__bf16*)(ws);            // [0,16) MB ; later Vt
  __bf16* Wqkvt = (__bf16*)(ws + 16 * MB);  // [16,22)  3072x1024
  __bf16* Wot   = (__bf16*)(ws + 22 * MB);  // [22,24)
  __bf16* Qb    = (__bf16*)(ws + 24 * MB);  // [24,40)
  __bf16* Kb    = (__bf16*)(ws + 40 * MB);  // [40,56)
  __bf16* Vb    = (__bf16*)(ws + 56 * MB);  // [56,72) ; later AO
  __bf16* Vtb   = (__bf16*)(ws);            // alias xb (dead after QKV GEMM)

  // 1) x -> bf16
  cvt_bf16_kernel<<<4096, 256, 0, stream>>>(x, xb, 8192 * D_MOD / 8);
  // 2) weight transposes into fused Wqkvt rows [0,1024)=Wq^T etc.
  dim3 tb(32, 8);
  transpose_cvt_kernel<<<dim3(32, 32), tb, 0, stream>>>(Wq, Wqkvt);
  transpose_cvt_kernel<<<dim3(32, 32), tb, 0, stream>>>(Wk, Wqkvt + 1024 * 1024);
  transpose_cvt_kernel<<<dim3(32, 32), tb, 0, stream>>>(Wv, Wqkvt + 2048 * 1024);
  transpose_cvt_kernel<<<dim3(32, 32), tb, 0, stream>>>(Wo, Wot);
  // 3) fused QKV projection: M=8192, N=3072 -> grid 64x12 = 768 = 3 rounds
  ugemm_kernel<0><<<768, 512, 0, stream>>>(xb, Wqkvt, bq, bk, bv, Qb, Kb, Vb,
                                           D_MOD, D_MOD, 0, 0, 0);
  // 4) V -> V^T per batch (xb dead -> Vt aliases it)
  transpose_v_kernel<<<dim3(64, 32, 4), tb, 0, stream>>>(Vb, Vtb);

  const bool batched = ws_size >= 137 * MB;
  if (batched) {
    float* S = (float*)(ws + 72 * MB);  // [72,136) fp32, 4 batches
    __bf16* AO = Vb;                    // alias V (dead after transpose)
    // 5) S = QK^T * scale, causal (lower-tri 128x256 tiles)
    ugemm_kernel<3><<<dim3(16, 8, 4), 512, 0, stream>>>(
        Qb, Kb, nullptr, nullptr, nullptr, S, nullptr, nullptr, D_MOD, D_MOD,
        TC, TC, TT);
    // 6) row softmax, P bf16 in-place (row stride 4096 bf16)
    softmax_kernel<<<dim3(T_SEQ, 4), 256, 0, stream>>>(S, TT);
    // 7) O = P V (A=P bf16 lda=4096, Bt=Vt ldb=2048, K=(i+1)*128)
    ugemm_kernel<2><<<dim3(64, 1, 4), 512, 0, stream>>>(
        (const __bf16*)S, Vtb, nullptr, nullptr, nullptr, AO, nullptr, nullptr,
        2 * T_SEQ, T_SEQ, TT * 2, (size_t)D_MOD * T_SEQ, TC);
    // 8) out projection (f32 out)
    ugemm_kernel<1><<<256, 512, 0, stream>>>(AO, Wot, bo, nullptr, nullptr,
                                             d_out, nullptr, nullptr, D_MOD,
                                             D_MOD, 0, 0, 0);
  } else {
    // per-batch fallback within 72MB: S reuses Vb slot, AO overwrites Qb
    float* S = (float*)(ws + 56 * MB);
    __bf16* AO = Qb;
    for (int b = 0; b < 4; ++b) {
      ugemm_kernel<3><<<dim3(16, 8, 1), 512, 0, stream>>>(
          Qb + b * TC, Kb + b * TC, nullptr, nullptr, nullptr, S, nullptr,
          nullptr, D_MOD, D_MOD, 0, 0, 0);
      softmax_kernel<<<dim3(T_SEQ, 1), 256, 0, stream>>>(S, 0);
      ugemm_kernel<2><<<dim3(64, 1, 1), 512, 0, stream>>>(
          (const __bf16*)S, Vtb + b * TC, nullptr, nullptr, nullptr,
          AO + b * TC, nullptr, nullptr, 2 * T_SEQ, T_SEQ, 0, 0, 0);
    }
    ugemm_kernel<1><<<256, 512, 0, stream>>>(AO, Wot, bo, nullptr, nullptr,
                                             d_out, nullptr, nullptr, D_MOD,
                                             D_MOD, 0, 0, 0);
  }
}

// Round 6
// 197.434 us; speedup vs baseline: 2.5841x; 1.0181x over previous
//
#include <hip/hip_runtime.h>
#include <hip/hip_bf16.h>
#include <stdint.h>

// ---------------------------------------------------------------------------
// MultiHeadAttention (no head split): out = softmax_causal((xWq)(xWk)^T/32)(xWv) Wo
// B=4, T=2048, C=1024, fp32 in/out, bf16 MFMA compute.
// Big GEMMs (QKV, QK): 256^2 8-phase schedule (round-3 structure, ran
// correctly in round 4) + round-5's PROVEN zero-conflict LDS swizzle
// (phys chunk = logical chunk ^ ((row>>1)&3); 0 SQ_LDS_BANK_CONFLICT).
// PV / out-proj: round-5 128x256 triple-buffer template (better grid balance).
// ---------------------------------------------------------------------------

typedef __attribute__((ext_vector_type(8))) __bf16 bf16x8;
typedef __attribute__((ext_vector_type(4))) float f32x4;

#define MFMA16(A, B, C) __builtin_amdgcn_mfma_f32_16x16x32_bf16(A, B, C, 0, 0, 0)
#define BAR() asm volatile("s_barrier" ::: "memory")

#define T_SEQ 2048
#define D_MOD 1024

static __device__ __forceinline__ void gload_lds16(const void* g, void* l) {
  __builtin_amdgcn_global_load_lds(
      (const __attribute__((address_space(1))) void*)g,
      (__attribute__((address_space(3))) void*)l, 16, 0, 0);
}

// ------------------------- elementwise fp32 -> bf16 ------------------------
__global__ void cvt_bf16_kernel(const float* __restrict__ in,
                                __bf16* __restrict__ out, int n8) {
  int i = blockIdx.x * blockDim.x + threadIdx.x;
  if (i < n8) {
    const float4* p = (const float4*)(in + (size_t)i * 8);
    float4 a = p[0], b = p[1];
    bf16x8 o;
    o[0] = (__bf16)a.x; o[1] = (__bf16)a.y; o[2] = (__bf16)a.z; o[3] = (__bf16)a.w;
    o[4] = (__bf16)b.x; o[5] = (__bf16)b.y; o[6] = (__bf16)b.z; o[7] = (__bf16)b.w;
    *(bf16x8*)(out + (size_t)i * 8) = o;
  }
}

// -------------------- W (K x N fp32) -> Wt (N x K bf16) --------------------
__global__ void transpose_cvt_kernel(const float* __restrict__ W,
                                     __bf16* __restrict__ Wt) {
  __shared__ float tile[32][33];
  int tx = threadIdx.x, ty = threadIdx.y;
  int bx = blockIdx.x * 32, by = blockIdx.y * 32;
#pragma unroll
  for (int i = 0; i < 4; i++)
    tile[ty + 8 * i][tx] = W[(size_t)(by + ty + 8 * i) * D_MOD + bx + tx];
  __syncthreads();
#pragma unroll
  for (int i = 0; i < 4; i++)
    Wt[(size_t)(bx + ty + 8 * i) * D_MOD + by + tx] = (__bf16)tile[tx][ty + 8 * i];
}

// -------------- V [b][2048][1024] bf16 -> Vt [b][1024][2048] ---------------
__global__ void transpose_v_kernel(const __bf16* __restrict__ V,
                                   __bf16* __restrict__ Vt) {
  __shared__ __bf16 tile[32][33];
  int tx = threadIdx.x, ty = threadIdx.y;
  int b = blockIdx.z;
  int t0 = blockIdx.x * 32, d0 = blockIdx.y * 32;
  const __bf16* Vb = V + (size_t)b * T_SEQ * D_MOD;
  __bf16* Vtb = Vt + (size_t)b * D_MOD * T_SEQ;
#pragma unroll
  for (int i = 0; i < 4; i++)
    tile[ty + 8 * i][tx] = Vb[(size_t)(t0 + ty + 8 * i) * D_MOD + d0 + tx];
  __syncthreads();
#pragma unroll
  for (int i = 0; i < 4; i++)
    Vtb[(size_t)(d0 + ty + 8 * i) * T_SEQ + t0 + tx] = tile[tx][ty + 8 * i];
}

// ================= 256^2 8-phase GEMM (swizzled, K=1024) ===================
// 512 thr = 8 waves (2M x 4N, wave tile 128x64), BK=64, dbuf 128KiB LDS.
// Half-tile LDS layout: [kk(2)@8192][row(128)@64B]; physical 16B chunk
// c' = c ^ ((row>>1)&3) (proven 0-conflict). Stage: linear LDS dest +
// pre-swizzled global source chunk. Counted vmcnt per round-3 schedule.
// MODE: 0 = QKV (bf16 out routed by 1024-col segment, bias b0/b1/b2)
//       3 = QK  (f32 out ldc=2048, *1/32, causal mask, skip j>i blocks)
template <int MG, int NG>
static __device__ __forceinline__ void mfma_quad(f32x4 (&acc)[8][4],
                                                 const bf16x8 (&aR)[4][2],
                                                 const bf16x8 (&bR)[2][2]) {
#pragma unroll
  for (int i = 0; i < 4; i++)
#pragma unroll
    for (int n = 0; n < 2; n++)
#pragma unroll
      for (int kk = 0; kk < 2; kk++)
        acc[MG * 4 + i][NG * 2 + n] =
            MFMA16(aR[i][kk], bR[n][kk], acc[MG * 4 + i][NG * 2 + n]);
}

template <int MODE>
__global__ __launch_bounds__(512, 2) void gemm8_kernel(
    const __bf16* __restrict__ A, const __bf16* __restrict__ Bt,
    const float* __restrict__ b0, const float* __restrict__ b1,
    const float* __restrict__ b2, void* __restrict__ o0,
    void* __restrict__ o1, void* __restrict__ o2, int lda, int ldb,
    size_t bsA, size_t bsB, size_t bsC) {
  constexpr int NT = 16;  // K = 1024
  __shared__ __align__(16) char lds[131072];
#define ABUF(p, h) (lds + ((p) * 2 + (h)) * 16384)
#define BBUF(p, h) (lds + 65536 + ((p) * 2 + (h)) * 16384)

  const int tid = threadIdx.x;
  const int w = tid >> 6, l = tid & 63;
  const int wr = w >> 2, wc = w & 3;  // 2 x 4 wave grid
  int bm, bn;
  if (MODE == 0) {
    const int cpx = gridDim.x >> 3;  // 384 % 8 == 0, bijective
    const int swz = ((int)blockIdx.x & 7) * cpx + ((int)blockIdx.x >> 3);
    bm = (swz / 12) * 256;
    bn = (swz % 12) * 256;
  } else {
    if ((int)blockIdx.y > (int)blockIdx.x) return;  // fully-masked tile
    bm = blockIdx.x * 256;
    bn = blockIdx.y * 256;
  }
  const int z = blockIdx.z;
  A += (size_t)z * bsA;
  Bt += (size_t)z * bsB;

  const int grow = l >> 2;                          // staged row in 16-stripe
  const int cswz = (l & 3) ^ ((l >> 3) & 3);        // pre-swizzled src chunk
  const int rlo = l & 15;                           // frag row within 16
  const int xsw = (((l >> 4) ^ ((l >> 1) & 3)) << 4);  // swizzled read chunk

#define STAGE_A(t, h)                                                        \
  {                                                                          \
    const __bf16* g = A + (size_t)(bm + (h) * 128 + w * 16 + grow) * lda +   \
                      (t) * 64 + cswz * 8;                                   \
    char* d = ABUF((t) & 1, h) + w * 1024 + l * 16;                          \
    gload_lds16(g, d);                                                       \
    gload_lds16(g + 32, d + 8192);                                           \
  }
#define STAGE_B(t, h)                                                        \
  {                                                                          \
    const __bf16* g = Bt + (size_t)(bn + (h) * 128 + w * 16 + grow) * ldb +  \
                      (t) * 64 + cswz * 8;                                   \
    char* d = BBUF((t) & 1, h) + w * 1024 + l * 16;                          \
    gload_lds16(g, d);                                                       \
    gload_lds16(g + 32, d + 8192);                                           \
  }
#define LDA_FRAG(p, g, i, kk)                                     \
  (*(const bf16x8*)(ABUF(p, wr) + (kk) * 8192 +                   \
                    ((g) * 64 + (i) * 16 + rlo) * 64 + xsw))
#define LDB_FRAG(p, g, n, kk)                                     \
  (*(const bf16x8*)(BBUF(p, (wc >> 1)) + (kk) * 8192 +            \
                    ((wc & 1) * 64 + (g) * 32 + (n) * 16 + rlo) * 64 + xsw))

  f32x4 acc[8][4] = {};
  // prologue: A(0), B(0), A(1)
  STAGE_A(0, 0); STAGE_A(0, 1);
  STAGE_B(0, 0); STAGE_B(0, 1);
  STAGE_A(1, 0); STAGE_A(1, 1);
  asm volatile("s_waitcnt vmcnt(4)" ::: "memory");  // A(0),B(0) landed
  BAR();

  for (int t = 0; t < NT; ++t) {
    const int p = t & 1;
    bf16x8 a[4][2], b[2][2];
    // phase a: read A-g0 + B-g0; stage B-h0(t+1); MFMA quad(0,0)
#pragma unroll
    for (int i = 0; i < 4; i++) {
      a[i][0] = LDA_FRAG(p, 0, i, 0);
      a[i][1] = LDA_FRAG(p, 0, i, 1);
    }
#pragma unroll
    for (int n = 0; n < 2; n++) {
      b[n][0] = LDB_FRAG(p, 0, n, 0);
      b[n][1] = LDB_FRAG(p, 0, n, 1);
    }
    if (t + 1 < NT) STAGE_B(t + 1, 0);
    BAR();
    __builtin_amdgcn_s_setprio(1);
    mfma_quad<0, 0>(acc, a, b);
    __builtin_amdgcn_s_setprio(0);
    BAR();
    // phase b: read B-g1; stage B-h1(t+1); MFMA quad(0,1)
    bf16x8 b2[2][2];
#pragma unroll
    for (int n = 0; n < 2; n++) {
      b2[n][0] = LDB_FRAG(p, 1, n, 0);
      b2[n][1] = LDB_FRAG(p, 1, n, 1);
    }
    if (t + 1 < NT) STAGE_B(t + 1, 1);
    BAR();
    __builtin_amdgcn_s_setprio(1);
    mfma_quad<0, 1>(acc, a, b2);
    __builtin_amdgcn_s_setprio(0);
    BAR();
    // phase c: read A-g1; MFMA quad(1,1)
#pragma unroll
    for (int i = 0; i < 4; i++) {
      a[i][0] = LDA_FRAG(p, 1, i, 0);
      a[i][1] = LDA_FRAG(p, 1, i, 1);
    }
    BAR();
    __builtin_amdgcn_s_setprio(1);
    mfma_quad<1, 1>(acc, a, b2);
    __builtin_amdgcn_s_setprio(0);
    BAR();
    // phase d: re-read B-g0; stage A(t+2); MFMA quad(1,0); counted vmcnt
#pragma unroll
    for (int n = 0; n < 2; n++) {
      b[n][0] = LDB_FRAG(p, 0, n, 0);
      b[n][1] = LDB_FRAG(p, 0, n, 1);
    }
    if (t + 2 < NT) {
      STAGE_A(t + 2, 0); STAGE_A(t + 2, 1);
      BAR();
      __builtin_amdgcn_s_setprio(1);
      mfma_quad<1, 0>(acc, a, b);
      __builtin_amdgcn_s_setprio(0);
      asm volatile("s_waitcnt vmcnt(4)" ::: "memory");
      BAR();
    } else {
      BAR();
      __builtin_amdgcn_s_setprio(1);
      mfma_quad<1, 0>(acc, a, b);
      __builtin_amdgcn_s_setprio(0);
      asm volatile("s_waitcnt vmcnt(0)" ::: "memory");
      BAR();
    }
  }

  // epilogue
  if (MODE == 0) {
    const int seg = bn >> 10;
    const float* bs = (seg == 0) ? b0 : (seg == 1) ? b1 : b2;
    __bf16* os = (__bf16*)((seg == 0) ? o0 : (seg == 1) ? o1 : o2);
    const int bnl = bn & 1023;
#pragma unroll
    for (int n4 = 0; n4 < 4; n4++) {
      int col = bnl + wc * 64 + n4 * 16 + rlo;
      float bvv = bs[col];
#pragma unroll
      for (int mi = 0; mi < 8; mi++) {
        int row = bm + wr * 128 + mi * 16 + (l >> 4) * 4;
#pragma unroll
        for (int r = 0; r < 4; r++)
          os[(size_t)(row + r) * D_MOD + col] = (__bf16)(acc[mi][n4][r] + bvv);
      }
    }
  } else {
    float* os = (float*)o0 + (size_t)z * bsC;
#pragma unroll
    for (int n4 = 0; n4 < 4; n4++) {
      int col = bn + wc * 64 + n4 * 16 + rlo;
#pragma unroll
      for (int mi = 0; mi < 8; mi++) {
        int rowb = bm + wr * 128 + mi * 16 + (l >> 4) * 4;
#pragma unroll
        for (int r = 0; r < 4; r++) {
          int row = rowb + r;
          float v = acc[mi][n4][r] * 0.03125f;  // 1/sqrt(1024)
          if (col > row) v = -1e30f;
          os[(size_t)row * T_SEQ + col] = v;
        }
      }
    }
  }
#undef ABUF
#undef BBUF
#undef STAGE_A
#undef STAGE_B
#undef LDA_FRAG
#undef LDB_FRAG
}

// ============ 128x256 triple-buffer GEMM (round-5, PV / out-proj) ==========
// MODE: 1 = out-proj (f32 out ldc=1024, bias b0)
//       2 = PV (bf16 out, no bias, K=(i+1)*128 triangular)
template <int MODE>
__global__ __launch_bounds__(512, 2) void ugemm_kernel(
    const __bf16* __restrict__ A, const __bf16* __restrict__ Bt,
    const float* __restrict__ b0, void* __restrict__ o0, int lda, int ldb,
    size_t bsA, size_t bsB, size_t bsC) {
  __shared__ __align__(16) char lds[147456];
#define ABUF(p3) (lds + (p3) * 16384)
#define BBUF(p3) (lds + 49152 + (p3) * 32768)

  const int tid = threadIdx.x;
  const int w = tid >> 6, l = tid & 63;
  const int wr = w >> 2, wc = w & 3;  // 2M x 4N wave grid
  const int z = blockIdx.z;

  int bm, bn, NT;
  if (MODE == 1) {
    const int cpx = gridDim.x >> 3;  // 256 % 8 == 0
    const int swz = ((int)blockIdx.x & 7) * cpx + ((int)blockIdx.x >> 3);
    bm = (swz >> 2) * 128; bn = (swz & 3) * 256; NT = 16;
  } else {
    const int i = (int)blockIdx.x >> 2;
    bm = i * 128; bn = ((int)blockIdx.x & 3) * 256; NT = (i + 1) * 2;
  }
  A += (size_t)z * bsA;
  Bt += (size_t)z * bsB;

  const int grow = w * 16 + (l >> 2);
  const int cswz = (l & 3) ^ ((l >> 3) & 3);
  const int rlo = l & 15;
  const int xsw = (((l >> 4) ^ ((l >> 1) & 3)) << 4);

#define STAGE_A(t, p3)                                                       \
  {                                                                          \
    const __bf16* g = A + (size_t)(bm + grow) * lda + (t) * 64 + cswz * 8;   \
    char* d = ABUF(p3) + w * 1024 + l * 16;                                  \
    gload_lds16(g, d);                                                       \
    gload_lds16(g + 32, d + 8192);                                           \
  }
#define STAGE_B(t, p3)                                                       \
  {                                                                          \
    const __bf16* g = Bt + (size_t)(bn + grow) * ldb + (t) * 64 + cswz * 8;  \
    char* d = BBUF(p3) + w * 1024 + l * 16;                                  \
    gload_lds16(g, d);                                                       \
    gload_lds16(g + 32, d + 16384);                                          \
    const __bf16* g2 = g + (size_t)128 * ldb;                                \
    gload_lds16(g2, d + 8192);                                               \
    gload_lds16(g2 + 32, d + 8192 + 16384);                                  \
  }
#define LDA_FRAG(p3, i, kk)                                       \
  (*(const bf16x8*)(ABUF(p3) + (kk) * 8192 +                      \
                    (wr * 64 + (i) * 16 + rlo) * 64 + xsw))
#define LDB_FRAG(p3, n, kk)                                       \
  (*(const bf16x8*)(BBUF(p3) + (kk) * 16384 +                     \
                    (wc * 64 + (n) * 16 + rlo) * 64 + xsw))

  f32x4 acc[4][4] = {};
  STAGE_A(0, 0); STAGE_B(0, 0);
  STAGE_A(1, 1); STAGE_B(1, 1);
  asm volatile("s_waitcnt vmcnt(6)" ::: "memory");
  BAR();

  int p = 0, pn2 = 2;
  for (int t = 0; t < NT; ++t) {
    bf16x8 af[4][2], bf01[2][2], bf23[2][2];
#pragma unroll
    for (int i = 0; i < 4; i++) {
      af[i][0] = LDA_FRAG(p, i, 0);
      af[i][1] = LDA_FRAG(p, i, 1);
    }
#pragma unroll
    for (int n = 0; n < 2; n++) {
      bf01[n][0] = LDB_FRAG(p, n, 0);
      bf01[n][1] = LDB_FRAG(p, n, 1);
    }
    if (t + 2 < NT) STAGE_A(t + 2, pn2);
    BAR();
    __builtin_amdgcn_s_setprio(1);
#pragma unroll
    for (int i = 0; i < 4; i++)
#pragma unroll
      for (int n = 0; n < 2; n++) {
        acc[i][n] = MFMA16(af[i][0], bf01[n][0], acc[i][n]);
        acc[i][n] = MFMA16(af[i][1], bf01[n][1], acc[i][n]);
      }
    __builtin_amdgcn_s_setprio(0);
    BAR();
#pragma unroll
    for (int n = 0; n < 2; n++) {
      bf23[n][0] = LDB_FRAG(p, n + 2, 0);
      bf23[n][1] = LDB_FRAG(p, n + 2, 1);
    }
    if (t + 2 < NT) STAGE_B(t + 2, pn2);
    BAR();
    __builtin_amdgcn_s_setprio(1);
#pragma unroll
    for (int i = 0; i < 4; i++)
#pragma unroll
      for (int n = 0; n < 2; n++) {
        acc[i][n + 2] = MFMA16(af[i][0], bf23[n][0], acc[i][n + 2]);
        acc[i][n + 2] = MFMA16(af[i][1], bf23[n][1], acc[i][n + 2]);
      }
    __builtin_amdgcn_s_setprio(0);
    if (t + 2 < NT) {
      asm volatile("s_waitcnt vmcnt(6)" ::: "memory");
    } else {
      asm volatile("s_waitcnt vmcnt(0)" ::: "memory");
    }
    BAR();
    p = (p + 1 == 3) ? 0 : p + 1;
    pn2 = (pn2 + 1 == 3) ? 0 : pn2 + 1;
  }

  if (MODE == 1) {
    float* os = (float*)o0;
#pragma unroll
    for (int n = 0; n < 4; n++) {
      int col = bn + wc * 64 + n * 16 + rlo;
      float bvv = b0[col];
#pragma unroll
      for (int m = 0; m < 4; m++) {
        int rowb = bm + wr * 64 + m * 16 + (l >> 4) * 4;
#pragma unroll
        for (int r = 0; r < 4; r++)
          os[(size_t)(rowb + r) * D_MOD + col] = acc[m][n][r] + bvv;
      }
    }
  } else {
    __bf16* os = (__bf16*)o0 + (size_t)z * bsC;
#pragma unroll
    for (int n = 0; n < 4; n++) {
      int col = bn + wc * 64 + n * 16 + rlo;
#pragma unroll
      for (int m = 0; m < 4; m++) {
        int rowb = bm + wr * 64 + m * 16 + (l >> 4) * 4;
#pragma unroll
        for (int r = 0; r < 4; r++)
          os[(size_t)(rowb + r) * D_MOD + col] = (__bf16)acc[m][n][r];
      }
    }
  }
#undef ABUF
#undef BBUF
#undef STAGE_A
#undef STAGE_B
#undef LDA_FRAG
#undef LDB_FRAG
}

// ----------------------- row softmax, P bf16 in-place ----------------------
__global__ __launch_bounds__(256) void softmax_kernel(float* __restrict__ S,
                                                      size_t bstride) {
  const int t = blockIdx.x, b = blockIdx.y;
  float* Srow = S + (size_t)b * bstride + (size_t)t * T_SEQ;
  __bf16* Prow = (__bf16*)Srow;
  const int L = ((t + 1) + 127) & ~127;
  const int tid = threadIdx.x;
  const int base = tid * 8;
  const bool act = base < L;
  float v[8];
  float m = -1e30f;
  if (act) {
    float4 a = *(const float4*)(Srow + base);
    float4 c = *(const float4*)(Srow + base + 4);
    v[0] = a.x; v[1] = a.y; v[2] = a.z; v[3] = a.w;
    v[4] = c.x; v[5] = c.y; v[6] = c.z; v[7] = c.w;
#pragma unroll
    for (int j = 0; j < 8; j++) m = fmaxf(m, v[j]);
  }
#pragma unroll
  for (int off = 1; off < 64; off <<= 1) m = fmaxf(m, __shfl_xor(m, off));
  __shared__ float redm[4], reds[4];
  const int wave = tid >> 6, lane = tid & 63;
  if (lane == 0) redm[wave] = m;
  __syncthreads();
  m = fmaxf(fmaxf(redm[0], redm[1]), fmaxf(redm[2], redm[3]));
  float p[8];
  float s = 0.f;
  if (act) {
#pragma unroll
    for (int j = 0; j < 8; j++) {
      p[j] = __expf(v[j] - m);
      s += p[j];
    }
  }
#pragma unroll
  for (int off = 1; off < 64; off <<= 1) s += __shfl_xor(s, off);
  if (lane == 0) reds[wave] = s;
  __syncthreads();  // fences: reads done before in-place bf16 writes
  const float inv = 1.0f / (reds[0] + reds[1] + reds[2] + reds[3]);
  if (act) {
    bf16x8 o;
#pragma unroll
    for (int j = 0; j < 8; j++) o[j] = (__bf16)(p[j] * inv);
    *(bf16x8*)(Prow + base) = o;
  }
}

// ---------------------------------------------------------------------------
extern "C" void kernel_launch(void* const* d_in, const int* in_sizes, int n_in,
                              void* d_out, int out_size, void* d_ws,
                              size_t ws_size, hipStream_t stream) {
  const float* x = (const float*)d_in[0];
  const float* Wq = (const float*)d_in[1];
  const float* bq = (const float*)d_in[2];
  const float* Wk = (const float*)d_in[3];
  const float* bk = (const float*)d_in[4];
  const float* Wv = (const float*)d_in[5];
  const float* bv = (const float*)d_in[6];
  const float* Wo = (const float*)d_in[7];
  const float* bo = (const float*)d_in[8];

  char* ws = (char*)d_ws;
  const size_t MB = 1u << 20;
  const size_t TC = (size_t)T_SEQ * D_MOD;  // 2M elems / batch
  const size_t TT = (size_t)T_SEQ * T_SEQ;  // 4M elems / batch
  __bf16* xb    = (__bf16*)(ws);            // [0,16) MB ; later Vt
  __bf16* Wqkvt = (__bf16*)(ws + 16 * MB);  // [16,22)  3072x1024
  __bf16* Wot   = (__bf16*)(ws + 22 * MB);  // [22,24)
  __bf16* Qb    = (__bf16*)(ws + 24 * MB);  // [24,40)
  __bf16* Kb    = (__bf16*)(ws + 40 * MB);  // [40,56)
  __bf16* Vb    = (__bf16*)(ws + 56 * MB);  // [56,72) ; later AO
  __bf16* Vtb   = (__bf16*)(ws);            // alias xb (dead after QKV GEMM)

  // 1) x -> bf16
  cvt_bf16_kernel<<<4096, 256, 0, stream>>>(x, xb, 8192 * D_MOD / 8);
  // 2) weight transposes into fused Wqkvt rows [0,1024)=Wq^T etc.
  dim3 tb(32, 8);
  transpose_cvt_kernel<<<dim3(32, 32), tb, 0, stream>>>(Wq, Wqkvt);
  transpose_cvt_kernel<<<dim3(32, 32), tb, 0, stream>>>(Wk, Wqkvt + 1024 * 1024);
  transpose_cvt_kernel<<<dim3(32, 32), tb, 0, stream>>>(Wv, Wqkvt + 2048 * 1024);
  transpose_cvt_kernel<<<dim3(32, 32), tb, 0, stream>>>(Wo, Wot);
  // 3) fused QKV projection: 256^2 8-phase, grid 32x12 = 384
  gemm8_kernel<0><<<384, 512, 0, stream>>>(xb, Wqkvt, bq, bk, bv, Qb, Kb, Vb,
                                           D_MOD, D_MOD, 0, 0, 0);
  // 4) V -> V^T per batch (xb dead -> Vt aliases it)
  transpose_v_kernel<<<dim3(64, 32, 4), tb, 0, stream>>>(Vb, Vtb);

  const bool batched = ws_size >= 137 * MB;
  if (batched) {
    float* S = (float*)(ws + 72 * MB);  // [72,136) fp32, 4 batches
    __bf16* AO = Vb;                    // alias V (dead after transpose)
    // 5) S = QK^T * scale, causal: 256^2 tiles, live j<=i (144 WGs)
    gemm8_kernel<3><<<dim3(8, 8, 4), 512, 0, stream>>>(
        Qb, Kb, nullptr, nullptr, nullptr, S, nullptr, nullptr, D_MOD, D_MOD,
        TC, TC, TT);
    // 6) row softmax, P bf16 in-place (row stride 4096 bf16)
    softmax_kernel<<<dim3(T_SEQ, 4), 256, 0, stream>>>(S, TT);
    // 7) O = P V (A=P bf16 lda=4096, Bt=Vt ldb=2048, K=(i+1)*128)
    ugemm_kernel<2><<<dim3(64, 1, 4), 512, 0, stream>>>(
        (const __bf16*)S, Vtb, nullptr, AO, 2 * T_SEQ, T_SEQ, TT * 2,
        (size_t)D_MOD * T_SEQ, TC);
    // 8) out projection (f32 out)
    ugemm_kernel<1><<<256, 512, 0, stream>>>(AO, Wot, bo, d_out, D_MOD, D_MOD,
                                             0, 0, 0);
  } else {
    // per-batch fallback within 72MB: S reuses Vb slot, AO overwrites Qb
    float* S = (float*)(ws + 56 * MB);
    __bf16* AO = Qb;
    for (int b = 0; b < 4; ++b) {
      gemm8_kernel<3><<<dim3(8, 8, 1), 512, 0, stream>>>(
          Qb + b * TC, Kb + b * TC, nullptr, nullptr, nullptr, S, nullptr,
          nullptr, D_MOD, D_MOD, 0, 0, 0);
      softmax_kernel<<<dim3(T_SEQ, 1), 256, 0, stream>>>(S, 0);
      ugemm_kernel<2><<<dim3(64, 1, 1), 512, 0, stream>>>(
          (const __bf16*)S, Vtb + b * TC, nullptr, AO + b * TC, 2 * T_SEQ,
          T_SEQ, 0, 0, 0);
    }
    ugemm_kernel<1><<<256, 512, 0, stream>>>(AO, Wot, bo, d_out, D_MOD, D_MOD,
                                             0, 0, 0);
  }
}

// Round 8
// 185.533 us; speedup vs baseline: 2.7498x; 1.0641x over previous
//
#include <hip/hip_runtime.h>
#include <hip/hip_bf16.h>
#include <stdint.h>

// ---------------------------------------------------------------------------
// MultiHeadAttention (no head split): out = softmax_causal((xWq)(xWk)^T/32)(xWv) Wo
// B=4, T=2048, C=1024, fp32 in/out, bf16 MFMA compute.
// QKV: 128x384-tile 3-phase GEMM (512 WGs = 2 FULL rounds), fused V^T epilogue.
//   Round-8 fix: corrected vmcnt ledger. Wave tiles (wc*96) span ALL B staging
//   stripes, so the WHOLE B(t) must land before tile t's first ds_read.
//   Schedule: ph0 stages all B(t+1); ph1 stages A(t+2); single vmcnt(2)/tile.
// QK: 256^2 8-phase. PV/outproj: 128x256 triple-buffer. Zero-conflict swizzle.
// ---------------------------------------------------------------------------

typedef __attribute__((ext_vector_type(8))) __bf16 bf16x8;
typedef __attribute__((ext_vector_type(4))) __bf16 bf16x4;
typedef __attribute__((ext_vector_type(4))) float f32x4;

#define MFMA16(A, B, C) __builtin_amdgcn_mfma_f32_16x16x32_bf16(A, B, C, 0, 0, 0)
#define BAR() asm volatile("s_barrier" ::: "memory")

#define T_SEQ 2048
#define D_MOD 1024

static __device__ __forceinline__ void gload_lds16(const void* g, void* l) {
  __builtin_amdgcn_global_load_lds(
      (const __attribute__((address_space(1))) void*)g,
      (__attribute__((address_space(3))) void*)l, 16, 0, 0);
}

// ------------------------- elementwise fp32 -> bf16 ------------------------
__global__ void cvt_bf16_kernel(const float* __restrict__ in,
                                __bf16* __restrict__ out, int n8) {
  int i = blockIdx.x * blockDim.x + threadIdx.x;
  if (i < n8) {
    const float4* p = (const float4*)(in + (size_t)i * 8);
    float4 a = p[0], b = p[1];
    bf16x8 o;
    o[0] = (__bf16)a.x; o[1] = (__bf16)a.y; o[2] = (__bf16)a.z; o[3] = (__bf16)a.w;
    o[4] = (__bf16)b.x; o[5] = (__bf16)b.y; o[6] = (__bf16)b.z; o[7] = (__bf16)b.w;
    *(bf16x8*)(out + (size_t)i * 8) = o;
  }
}

// ---------- all four W (K x N fp32) -> Wt (N x K bf16), one launch ---------
__global__ void transpose_cvt4_kernel(const float* __restrict__ Wq,
                                      const float* __restrict__ Wk,
                                      const float* __restrict__ Wv,
                                      const float* __restrict__ Wo,
                                      __bf16* __restrict__ Wqkvt,
                                      __bf16* __restrict__ Wot) {
  __shared__ float tile[32][33];
  const int z = blockIdx.z;
  const float* W = (z == 0) ? Wq : (z == 1) ? Wk : (z == 2) ? Wv : Wo;
  __bf16* Wt = (z < 3) ? (Wqkvt + (size_t)z * 1024 * 1024) : Wot;
  int tx = threadIdx.x, ty = threadIdx.y;
  int bx = blockIdx.x * 32, by = blockIdx.y * 32;
#pragma unroll
  for (int i = 0; i < 4; i++)
    tile[ty + 8 * i][tx] = W[(size_t)(by + ty + 8 * i) * D_MOD + bx + tx];
  __syncthreads();
#pragma unroll
  for (int i = 0; i < 4; i++)
    Wt[(size_t)(bx + ty + 8 * i) * D_MOD + by + tx] = (__bf16)tile[tx][ty + 8 * i];
}

// ================= QKV: 128x384-tile 3-phase GEMM, 512 WGs =================
// C[8192][3072] = x @ Wqkvt^T + bias.  8 waves (2M x 4N), wave tile 64x96,
// BK=64, acc[4][6].  LDS 128KiB: A dbuf 2x16KiB [kk@8192][row128@64B],
// B dbuf 2x48KiB [kk@24576][row384@64B]; zero-conflict swizzle both sides.
// LEDGER (uniform, 1 wait/tile): prologue {A(0),B(0)x3,A(1); vmcnt(2)}.
// Tile t: ph0 {read A+Bg0; stage B(t+1)x3 -> p^1; BAR; MFMA; BAR}
//         ph1 {read Bg1; stage A(t+2) -> p;      BAR; MFMA; BAR}
//         ph2 {read Bg2;                          BAR; MFMA;
//              vmcnt(t<NT-2 ? 2 : 0); BAR}
// In-flight order at tile-t end: A(t+1),B(t+1)x6,A(t+2) -> vmcnt(2) lands
// A(t+1)+ALL B(t+1), leaving A(t+2): tile t+1's reads are fully covered.
// Epilogue: Q/K segments row-major; V segment written TRANSPOSED to Vt.
__global__ __launch_bounds__(512, 2) void qkv384_kernel(
    const __bf16* __restrict__ A, const __bf16* __restrict__ Bt,
    const float* __restrict__ bq, const float* __restrict__ bk,
    const float* __restrict__ bv, __bf16* __restrict__ Qo,
    __bf16* __restrict__ Ko, __bf16* __restrict__ Vto) {
  constexpr int NT = 16;  // K = 1024
  __shared__ __align__(16) char lds[131072];
#define ABUF(p) (lds + (p) * 16384)
#define BBUF(p) (lds + 32768 + (p) * 49152)

  const int tid = threadIdx.x;
  const int w = tid >> 6, l = tid & 63;
  const int wr = w >> 2, wc = w & 3;  // 2M x 4N
  // XCD bijective swizzle (512 % 8 == 0)
  const int cpx = gridDim.x >> 3;
  const int swz = ((int)blockIdx.x & 7) * cpx + ((int)blockIdx.x >> 3);
  const int bm = (swz >> 3) * 128;   // 64 m-tiles
  const int bn = (swz & 7) * 384;    // 8 n-tiles

  const int cswz = (l & 3) ^ ((l >> 3) & 3);           // staging src chunk
  const int rlo = l & 15;                              // frag row within 16
  const int xsw = (((l >> 4) ^ ((l >> 1) & 3)) << 4);  // frag read chunk

#define STAGE_A(t, p)                                                     \
  {                                                                       \
    const __bf16* g = A + (size_t)(bm + w * 16 + (l >> 2)) * 1024 +       \
                      (t) * 64 + cswz * 8;                                \
    char* d = ABUF(p) + w * 1024 + l * 16;                                \
    gload_lds16(g, d);                                                    \
    gload_lds16(g + 32, d + 8192);                                        \
  }
#define STAGE_B(t, p, gch)                                                \
  {                                                                       \
    const __bf16* g = Bt +                                                \
        (size_t)(bn + ((gch) * 8 + w) * 16 + (l >> 2)) * 1024 +           \
        (t) * 64 + cswz * 8;                                              \
    char* d = BBUF(p) + ((gch) * 8 + w) * 1024 + l * 16;                  \
    gload_lds16(g, d);                                                    \
    gload_lds16(g + 32, d + 24576);                                       \
  }
#define LDA_FRAG(p, i, kk)                                        \
  (*(const bf16x8*)(ABUF(p) + (kk) * 8192 +                       \
                    (wr * 64 + (i) * 16 + rlo) * 64 + xsw))
#define LDB_FRAG(p, gch, n, kk)                                   \
  (*(const bf16x8*)(BBUF(p) + (kk) * 24576 +                      \
                    (wc * 96 + (gch) * 32 + (n) * 16 + rlo) * 64 + xsw))

  f32x4 acc[4][6] = {};
  // prologue: A(0), B(0) g0..g2, A(1); drain A(0)+B(0) (first 8 of 10)
  STAGE_A(0, 0);
  STAGE_B(0, 0, 0); STAGE_B(0, 0, 1); STAGE_B(0, 0, 2);
  STAGE_A(1, 1);
  asm volatile("s_waitcnt vmcnt(2)" ::: "memory");
  BAR();

  for (int t = 0; t < NT; ++t) {
    const int p = t & 1;
    bf16x8 a[4][2], bfr[2][2];
    // ---- ph0: A frags + B g0; stage ALL B(t+1); MFMA g0 ----
#pragma unroll
    for (int i = 0; i < 4; i++) {
      a[i][0] = LDA_FRAG(p, i, 0);
      a[i][1] = LDA_FRAG(p, i, 1);
    }
#pragma unroll
    for (int n = 0; n < 2; n++) {
      bfr[n][0] = LDB_FRAG(p, 0, n, 0);
      bfr[n][1] = LDB_FRAG(p, 0, n, 1);
    }
    if (t + 1 < NT) {
      STAGE_B(t + 1, p ^ 1, 0);
      STAGE_B(t + 1, p ^ 1, 1);
      STAGE_B(t + 1, p ^ 1, 2);
    }
    BAR();
    __builtin_amdgcn_s_setprio(1);
#pragma unroll
    for (int i = 0; i < 4; i++)
#pragma unroll
      for (int n = 0; n < 2; n++) {
        acc[i][n] = MFMA16(a[i][0], bfr[n][0], acc[i][n]);
        acc[i][n] = MFMA16(a[i][1], bfr[n][1], acc[i][n]);
      }
    __builtin_amdgcn_s_setprio(0);
    BAR();
    // ---- ph1: B g1; stage A(t+2) into buf p (A(t) reads done at ph0 BAR) --
#pragma unroll
    for (int n = 0; n < 2; n++) {
      bfr[n][0] = LDB_FRAG(p, 1, n, 0);
      bfr[n][1] = LDB_FRAG(p, 1, n, 1);
    }
    if (t + 2 < NT) STAGE_A(t + 2, p);
    BAR();
    __builtin_amdgcn_s_setprio(1);
#pragma unroll
    for (int i = 0; i < 4; i++)
#pragma unroll
      for (int n = 0; n < 2; n++) {
        acc[i][2 + n] = MFMA16(a[i][0], bfr[n][0], acc[i][2 + n]);
        acc[i][2 + n] = MFMA16(a[i][1], bfr[n][1], acc[i][2 + n]);
      }
    __builtin_amdgcn_s_setprio(0);
    BAR();
    // ---- ph2: B g2; MFMA g2; single per-tile wait ----
#pragma unroll
    for (int n = 0; n < 2; n++) {
      bfr[n][0] = LDB_FRAG(p, 2, n, 0);
      bfr[n][1] = LDB_FRAG(p, 2, n, 1);
    }
    BAR();
    __builtin_amdgcn_s_setprio(1);
#pragma unroll
    for (int i = 0; i < 4; i++)
#pragma unroll
      for (int n = 0; n < 2; n++) {
        acc[i][4 + n] = MFMA16(a[i][0], bfr[n][0], acc[i][4 + n]);
        acc[i][4 + n] = MFMA16(a[i][1], bfr[n][1], acc[i][4 + n]);
      }
    __builtin_amdgcn_s_setprio(0);
    if (t < NT - 2) asm volatile("s_waitcnt vmcnt(2)" ::: "memory");
    else asm volatile("s_waitcnt vmcnt(0)" ::: "memory");
    BAR();
  }

  // ---- epilogue: Q/K row-major; V segment transposed to Vt[b][d][t] ----
  const int l4 = (l >> 4) * 4;
#pragma unroll
  for (int gch = 0; gch < 3; gch++)
#pragma unroll
    for (int n = 0; n < 2; n++) {
      const int cbase = bn + wc * 96 + gch * 32 + n * 16;  // mult of 16
      const int seg = cbase >> 10;
      const int lcol = (cbase & 1023) + rlo;
      const int an = gch * 2 + n;
      if (seg < 2) {
        const float* bs = seg ? bk : bq;
        __bf16* os = seg ? Ko : Qo;
        const float bvv = bs[lcol];
#pragma unroll
        for (int i = 0; i < 4; i++) {
          const int rowb = bm + wr * 64 + i * 16 + l4;
#pragma unroll
          for (int r = 0; r < 4; r++)
            os[(size_t)(rowb + r) * D_MOD + lcol] =
                (__bf16)(acc[i][an][r] + bvv);
        }
      } else {
        const float bvv = bv[lcol];
#pragma unroll
        for (int i = 0; i < 4; i++) {
          const int rowb = bm + wr * 64 + i * 16 + l4;  // mult of 4
          const int z = rowb >> 11, tt = rowb & 2047;
          bf16x4 pk;
#pragma unroll
          for (int r = 0; r < 4; r++) pk[r] = (__bf16)(acc[i][an][r] + bvv);
          *(bf16x4*)(Vto + (size_t)z * (D_MOD * T_SEQ) +
                     (size_t)lcol * T_SEQ + tt) = pk;
        }
      }
    }
#undef ABUF
#undef BBUF
#undef STAGE_A
#undef STAGE_B
#undef LDA_FRAG
#undef LDB_FRAG
}

// ================= 256^2 8-phase GEMM (QK: causal, f32 out) ================
template <int MG, int NG>
static __device__ __forceinline__ void mfma_quad(f32x4 (&acc)[8][4],
                                                 const bf16x8 (&aR)[4][2],
                                                 const bf16x8 (&bR)[2][2]) {
#pragma unroll
  for (int i = 0; i < 4; i++)
#pragma unroll
    for (int n = 0; n < 2; n++)
#pragma unroll
      for (int kk = 0; kk < 2; kk++)
        acc[MG * 4 + i][NG * 2 + n] =
            MFMA16(aR[i][kk], bR[n][kk], acc[MG * 4 + i][NG * 2 + n]);
}

__global__ __launch_bounds__(512, 2) void qk_kernel(
    const __bf16* __restrict__ A, const __bf16* __restrict__ Bt,
    float* __restrict__ So, size_t bsA, size_t bsB, size_t bsC) {
  constexpr int NT = 16;
  __shared__ __align__(16) char lds[131072];
#define ABUF(p, h) (lds + ((p) * 2 + (h)) * 16384)
#define BBUF(p, h) (lds + 65536 + ((p) * 2 + (h)) * 16384)

  const int tid = threadIdx.x;
  const int w = tid >> 6, l = tid & 63;
  const int wr = w >> 2, wc = w & 3;
  if ((int)blockIdx.y > (int)blockIdx.x) return;
  const int bm = blockIdx.x * 256, bn = blockIdx.y * 256;
  const int z = blockIdx.z;
  A += (size_t)z * bsA;
  Bt += (size_t)z * bsB;

  const int grow = l >> 2;
  const int cswz = (l & 3) ^ ((l >> 3) & 3);
  const int rlo = l & 15;
  const int xsw = (((l >> 4) ^ ((l >> 1) & 3)) << 4);

#define STAGE_A(t, h)                                                       \
  {                                                                         \
    const __bf16* g = A + (size_t)(bm + (h) * 128 + w * 16 + grow) * 1024 + \
                      (t) * 64 + cswz * 8;                                  \
    char* d = ABUF((t) & 1, h) + w * 1024 + l * 16;                         \
    gload_lds16(g, d);                                                      \
    gload_lds16(g + 32, d + 8192);                                          \
  }
#define STAGE_B(t, h)                                                       \
  {                                                                         \
    const __bf16* g = Bt + (size_t)(bn + (h) * 128 + w * 16 + grow) * 1024 +\
                      (t) * 64 + cswz * 8;                                  \
    char* d = BBUF((t) & 1, h) + w * 1024 + l * 16;                         \
    gload_lds16(g, d);                                                      \
    gload_lds16(g + 32, d + 8192);                                          \
  }
#define LDA_FRAG(p, g, i, kk)                                     \
  (*(const bf16x8*)(ABUF(p, wr) + (kk) * 8192 +                   \
                    ((g) * 64 + (i) * 16 + rlo) * 64 + xsw))
#define LDB_FRAG(p, g, n, kk)                                     \
  (*(const bf16x8*)(BBUF(p, (wc >> 1)) + (kk) * 8192 +            \
                    ((wc & 1) * 64 + (g) * 32 + (n) * 16 + rlo) * 64 + xsw))

  f32x4 acc[8][4] = {};
  STAGE_A(0, 0); STAGE_A(0, 1);
  STAGE_B(0, 0); STAGE_B(0, 1);
  STAGE_A(1, 0); STAGE_A(1, 1);
  asm volatile("s_waitcnt vmcnt(4)" ::: "memory");
  BAR();

  for (int t = 0; t < NT; ++t) {
    const int p = t & 1;
    bf16x8 a[4][2], b[2][2];
#pragma unroll
    for (int i = 0; i < 4; i++) {
      a[i][0] = LDA_FRAG(p, 0, i, 0);
      a[i][1] = LDA_FRAG(p, 0, i, 1);
    }
#pragma unroll
    for (int n = 0; n < 2; n++) {
      b[n][0] = LDB_FRAG(p, 0, n, 0);
      b[n][1] = LDB_FRAG(p, 0, n, 1);
    }
    if (t + 1 < NT) STAGE_B(t + 1, 0);
    BAR();
    __builtin_amdgcn_s_setprio(1);
    mfma_quad<0, 0>(acc, a, b);
    __builtin_amdgcn_s_setprio(0);
    BAR();
    bf16x8 b2[2][2];
#pragma unroll
    for (int n = 0; n < 2; n++) {
      b2[n][0] = LDB_FRAG(p, 1, n, 0);
      b2[n][1] = LDB_FRAG(p, 1, n, 1);
    }
    if (t + 1 < NT) STAGE_B(t + 1, 1);
    BAR();
    __builtin_amdgcn_s_setprio(1);
    mfma_quad<0, 1>(acc, a, b2);
    __builtin_amdgcn_s_setprio(0);
    BAR();
#pragma unroll
    for (int i = 0; i < 4; i++) {
      a[i][0] = LDA_FRAG(p, 1, i, 0);
      a[i][1] = LDA_FRAG(p, 1, i, 1);
    }
    BAR();
    __builtin_amdgcn_s_setprio(1);
    mfma_quad<1, 1>(acc, a, b2);
    __builtin_amdgcn_s_setprio(0);
    BAR();
#pragma unroll
    for (int n = 0; n < 2; n++) {
      b[n][0] = LDB_FRAG(p, 0, n, 0);
      b[n][1] = LDB_FRAG(p, 0, n, 1);
    }
    if (t + 2 < NT) {
      STAGE_A(t + 2, 0); STAGE_A(t + 2, 1);
      BAR();
      __builtin_amdgcn_s_setprio(1);
      mfma_quad<1, 0>(acc, a, b);
      __builtin_amdgcn_s_setprio(0);
      asm volatile("s_waitcnt vmcnt(4)" ::: "memory");
      BAR();
    } else {
      BAR();
      __builtin_amdgcn_s_setprio(1);
      mfma_quad<1, 0>(acc, a, b);
      __builtin_amdgcn_s_setprio(0);
      asm volatile("s_waitcnt vmcnt(0)" ::: "memory");
      BAR();
    }
  }

  float* os = So + (size_t)z * bsC;
#pragma unroll
  for (int n4 = 0; n4 < 4; n4++) {
    int col = bn + wc * 64 + n4 * 16 + rlo;
#pragma unroll
    for (int mi = 0; mi < 8; mi++) {
      int rowb = bm + wr * 128 + mi * 16 + (l >> 4) * 4;
#pragma unroll
      for (int r = 0; r < 4; r++) {
        int row = rowb + r;
        float v = acc[mi][n4][r] * 0.03125f;  // 1/sqrt(1024)
        if (col > row) v = -1e30f;
        os[(size_t)row * T_SEQ + col] = v;
      }
    }
  }
#undef ABUF
#undef BBUF
#undef STAGE_A
#undef STAGE_B
#undef LDA_FRAG
#undef LDB_FRAG
}

// ============ 128x256 triple-buffer GEMM (PV / out-proj) ===================
// MODE: 1 = out-proj (f32 out ldc=1024, bias b0)
//       2 = PV (bf16 out, no bias, K=(i+1)*128 triangular)
template <int MODE>
__global__ __launch_bounds__(512, 2) void ugemm_kernel(
    const __bf16* __restrict__ A, const __bf16* __restrict__ Bt,
    const float* __restrict__ b0, void* __restrict__ o0, int lda, int ldb,
    size_t bsA, size_t bsB, size_t bsC) {
  __shared__ __align__(16) char lds[147456];
#define ABUF(p3) (lds + (p3) * 16384)
#define BBUF(p3) (lds + 49152 + (p3) * 32768)

  const int tid = threadIdx.x;
  const int w = tid >> 6, l = tid & 63;
  const int wr = w >> 2, wc = w & 3;
  const int z = blockIdx.z;

  int bm, bn, NT;
  if (MODE == 1) {
    const int cpx = gridDim.x >> 3;
    const int swz = ((int)blockIdx.x & 7) * cpx + ((int)blockIdx.x >> 3);
    bm = (swz >> 2) * 128; bn = (swz & 3) * 256; NT = 16;
  } else {
    const int i = (int)blockIdx.x >> 2;
    bm = i * 128; bn = ((int)blockIdx.x & 3) * 256; NT = (i + 1) * 2;
  }
  A += (size_t)z * bsA;
  Bt += (size_t)z * bsB;

  const int grow = w * 16 + (l >> 2);
  const int cswz = (l & 3) ^ ((l >> 3) & 3);
  const int rlo = l & 15;
  const int xsw = (((l >> 4) ^ ((l >> 1) & 3)) << 4);

#define STAGE_A(t, p3)                                                       \
  {                                                                          \
    const __bf16* g = A + (size_t)(bm + grow) * lda + (t) * 64 + cswz * 8;   \
    char* d = ABUF(p3) + w * 1024 + l * 16;                                  \
    gload_lds16(g, d);                                                       \
    gload_lds16(g + 32, d + 8192);                                           \
  }
#define STAGE_B(t, p3)                                                       \
  {                                                                          \
    const __bf16* g = Bt + (size_t)(bn + grow) * ldb + (t) * 64 + cswz * 8;  \
    char* d = BBUF(p3) + w * 1024 + l * 16;                                  \
    gload_lds16(g, d);                                                       \
    gload_lds16(g + 32, d + 16384);                                          \
    const __bf16* g2 = g + (size_t)128 * ldb;                                \
    gload_lds16(g2, d + 8192);                                               \
    gload_lds16(g2 + 32, d + 8192 + 16384);                                  \
  }
#define LDA_FRAG(p3, i, kk)                                       \
  (*(const bf16x8*)(ABUF(p3) + (kk) * 8192 +                      \
                    (wr * 64 + (i) * 16 + rlo) * 64 + xsw))
#define LDB_FRAG(p3, n, kk)                                       \
  (*(const bf16x8*)(BBUF(p3) + (kk) * 16384 +                     \
                    (wc * 64 + (n) * 16 + rlo) * 64 + xsw))

  f32x4 acc[4][4] = {};
  STAGE_A(0, 0); STAGE_B(0, 0);
  STAGE_A(1, 1); STAGE_B(1, 1);
  asm volatile("s_waitcnt vmcnt(6)" ::: "memory");
  BAR();

  int p = 0, pn2 = 2;
  for (int t = 0; t < NT; ++t) {
    bf16x8 af[4][2], bf01[2][2], bf23[2][2];
#pragma unroll
    for (int i = 0; i < 4; i++) {
      af[i][0] = LDA_FRAG(p, i, 0);
      af[i][1] = LDA_FRAG(p, i, 1);
    }
#pragma unroll
    for (int n = 0; n < 2; n++) {
      bf01[n][0] = LDB_FRAG(p, n, 0);
      bf01[n][1] = LDB_FRAG(p, n, 1);
    }
    if (t + 2 < NT) STAGE_A(t + 2, pn2);
    BAR();
    __builtin_amdgcn_s_setprio(1);
#pragma unroll
    for (int i = 0; i < 4; i++)
#pragma unroll
      for (int n = 0; n < 2; n++) {
        acc[i][n] = MFMA16(af[i][0], bf01[n][0], acc[i][n]);
        acc[i][n] = MFMA16(af[i][1], bf01[n][1], acc[i][n]);
      }
    __builtin_amdgcn_s_setprio(0);
    BAR();
#pragma unroll
    for (int n = 0; n < 2; n++) {
      bf23[n][0] = LDB_FRAG(p, n + 2, 0);
      bf23[n][1] = LDB_FRAG(p, n + 2, 1);
    }
    if (t + 2 < NT) STAGE_B(t + 2, pn2);
    BAR();
    __builtin_amdgcn_s_setprio(1);
#pragma unroll
    for (int i = 0; i < 4; i++)
#pragma unroll
      for (int n = 0; n < 2; n++) {
        acc[i][n + 2] = MFMA16(af[i][0], bf23[n][0], acc[i][n + 2]);
        acc[i][n + 2] = MFMA16(af[i][1], bf23[n][1], acc[i][n + 2]);
      }
    __builtin_amdgcn_s_setprio(0);
    if (t + 2 < NT) {
      asm volatile("s_waitcnt vmcnt(6)" ::: "memory");
    } else {
      asm volatile("s_waitcnt vmcnt(0)" ::: "memory");
    }
    BAR();
    p = (p + 1 == 3) ? 0 : p + 1;
    pn2 = (pn2 + 1 == 3) ? 0 : pn2 + 1;
  }

  if (MODE == 1) {
    float* os = (float*)o0;
#pragma unroll
    for (int n = 0; n < 4; n++) {
      int col = bn + wc * 64 + n * 16 + rlo;
      float bvv = b0[col];
#pragma unroll
      for (int m = 0; m < 4; m++) {
        int rowb = bm + wr * 64 + m * 16 + (l >> 4) * 4;
#pragma unroll
        for (int r = 0; r < 4; r++)
          os[(size_t)(rowb + r) * D_MOD + col] = acc[m][n][r] + bvv;
      }
    }
  } else {
    __bf16* os = (__bf16*)o0 + (size_t)z * bsC;
#pragma unroll
    for (int n = 0; n < 4; n++) {
      int col = bn + wc * 64 + n * 16 + rlo;
#pragma unroll
      for (int m = 0; m < 4; m++) {
        int rowb = bm + wr * 64 + m * 16 + (l >> 4) * 4;
#pragma unroll
        for (int r = 0; r < 4; r++)
          os[(size_t)(rowb + r) * D_MOD + col] = (__bf16)acc[m][n][r];
      }
    }
  }
#undef ABUF
#undef BBUF
#undef STAGE_A
#undef STAGE_B
#undef LDA_FRAG
#undef LDB_FRAG
}

// ----------------------- row softmax, P bf16 in-place ----------------------
__global__ __launch_bounds__(256) void softmax_kernel(float* __restrict__ S,
                                                      size_t bstride) {
  const int t = blockIdx.x, b = blockIdx.y;
  float* Srow = S + (size_t)b * bstride + (size_t)t * T_SEQ;
  __bf16* Prow = (__bf16*)Srow;
  const int L = ((t + 1) + 127) & ~127;
  const int tid = threadIdx.x;
  const int base = tid * 8;
  const bool act = base < L;
  float v[8];
  float m = -1e30f;
  if (act) {
    float4 a = *(const float4*)(Srow + base);
    float4 c = *(const float4*)(Srow + base + 4);
    v[0] = a.x; v[1] = a.y; v[2] = a.z; v[3] = a.w;
    v[4] = c.x; v[5] = c.y; v[6] = c.z; v[7] = c.w;
#pragma unroll
    for (int j = 0; j < 8; j++) m = fmaxf(m, v[j]);
  }
#pragma unroll
  for (int off = 1; off < 64; off <<= 1) m = fmaxf(m, __shfl_xor(m, off));
  __shared__ float redm[4], reds[4];
  const int wave = tid >> 6, lane = tid & 63;
  if (lane == 0) redm[wave] = m;
  __syncthreads();
  m = fmaxf(fmaxf(redm[0], redm[1]), fmaxf(redm[2], redm[3]));
  float p[8];
  float s = 0.f;
  if (act) {
#pragma unroll
    for (int j = 0; j < 8; j++) {
      p[j] = __expf(v[j] - m);
      s += p[j];
    }
  }
#pragma unroll
  for (int off = 1; off < 64; off <<= 1) s += __shfl_xor(s, off);
  if (lane == 0) reds[wave] = s;
  __syncthreads();  // fences: reads done before in-place bf16 writes
  const float inv = 1.0f / (reds[0] + reds[1] + reds[2] + reds[3]);
  if (act) {
    bf16x8 o;
#pragma unroll
    for (int j = 0; j < 8; j++) o[j] = (__bf16)(p[j] * inv);
    *(bf16x8*)(Prow + base) = o;
  }
}

// ---------------------------------------------------------------------------
extern "C" void kernel_launch(void* const* d_in, const int* in_sizes, int n_in,
                              void* d_out, int out_size, void* d_ws,
                              size_t ws_size, hipStream_t stream) {
  const float* x = (const float*)d_in[0];
  const float* Wq = (const float*)d_in[1];
  const float* bq = (const float*)d_in[2];
  const float* Wk = (const float*)d_in[3];
  const float* bk = (const float*)d_in[4];
  const float* Wv = (const float*)d_in[5];
  const float* bv = (const float*)d_in[6];
  const float* Wo = (const float*)d_in[7];
  const float* bo = (const float*)d_in[8];

  char* ws = (char*)d_ws;
  const size_t MB = 1u << 20;
  const size_t TC = (size_t)T_SEQ * D_MOD;  // 2M elems / batch
  const size_t TT = (size_t)T_SEQ * T_SEQ;  // 4M elems / batch
  __bf16* xb    = (__bf16*)(ws);            // [0,16) MB ; dead after QKV
  __bf16* Wqkvt = (__bf16*)(ws + 16 * MB);  // [16,22)  3072x1024
  __bf16* Wot   = (__bf16*)(ws + 22 * MB);  // [22,24)
  __bf16* Qb    = (__bf16*)(ws + 24 * MB);  // [24,40) ; later AO
  __bf16* Kb    = (__bf16*)(ws + 40 * MB);  // [40,56)
  __bf16* Vtb   = (__bf16*)(ws + 56 * MB);  // [56,72)  V^T direct from QKV

  // 1) x -> bf16
  cvt_bf16_kernel<<<4096, 256, 0, stream>>>(x, xb, 8192 * D_MOD / 8);
  // 2) weight transposes (one dispatch)
  transpose_cvt4_kernel<<<dim3(32, 32, 4), dim3(32, 8), 0, stream>>>(
      Wq, Wk, Wv, Wo, Wqkvt, Wot);
  // 3) fused QKV projection: 128x384 tiles, 512 WGs = 2 full rounds;
  //    V segment written directly transposed to Vtb.
  qkv384_kernel<<<512, 512, 0, stream>>>(xb, Wqkvt, bq, bk, bv, Qb, Kb, Vtb);

  const bool batched = ws_size >= 137 * MB;
  if (batched) {
    float* S = (float*)(ws + 72 * MB);  // [72,136) fp32, 4 batches
    __bf16* AO = Qb;                    // Q dead after QK
    // 4) S = QK^T * scale, causal: 256^2 tiles, live j<=i
    qk_kernel<<<dim3(8, 8, 4), 512, 0, stream>>>(Qb, Kb, S, TC, TC, TT);
    // 5) row softmax, P bf16 in-place (row stride 4096 bf16)
    softmax_kernel<<<dim3(T_SEQ, 4), 256, 0, stream>>>(S, TT);
    // 6) O = P V (A=P bf16 lda=4096, Bt=Vt ldb=2048, K=(i+1)*128)
    ugemm_kernel<2><<<dim3(64, 1, 4), 512, 0, stream>>>(
        (const __bf16*)S, Vtb, nullptr, AO, 2 * T_SEQ, T_SEQ, TT * 2, TC, TC);
    // 7) out projection (f32 out)
    ugemm_kernel<1><<<256, 512, 0, stream>>>(AO, Wot, bo, d_out, D_MOD, D_MOD,
                                             0, 0, 0);
  } else {
    // per-batch fallback: S reuses xb region (dead after QKV), AO over Qb
    float* S = (float*)(ws);
    __bf16* AO = Qb;
    for (int b = 0; b < 4; ++b) {
      qk_kernel<<<dim3(8, 8, 1), 512, 0, stream>>>(Qb + b * TC, Kb + b * TC, S,
                                                   0, 0, 0);
      softmax_kernel<<<dim3(T_SEQ, 1), 256, 0, stream>>>(S, 0);
      ugemm_kernel<2><<<dim3(64, 1, 1), 512, 0, stream>>>(
          (const __bf16*)S, Vtb + b * TC, nullptr, AO + b * TC, 2 * T_SEQ,
          T_SEQ, 0, 0, 0);
    }
    ugemm_kernel<1><<<256, 512, 0, stream>>>(AO, Wot, bo, d_out, D_MOD, D_MOD,
                                             0, 0, 0);
  }
}

// Round 9
// 175.091 us; speedup vs baseline: 2.9138x; 1.0596x over previous
//
#include <hip/hip_runtime.h>
#include <hip/hip_bf16.h>
#include <stdint.h>

// ---------------------------------------------------------------------------
// MultiHeadAttention (no head split): out = softmax_causal((xWq)(xWk)^T/32)(xWv) Wo
// B=4, T=2048, C=1024, fp32 in/out, bf16 MFMA compute.
// QKV: 128x384 3-phase GEMM, register-pipelined sections (reads for section
//      k+1 issue inside section k -> LDS and matrix pipes overlap).
// QK: 256^2 8-phase. PV: 128x128 paired-triangular (34 steps/WG, 1 round).
// outproj: 128x256 triple-buffer. Zero-conflict swizzle everywhere.
// ---------------------------------------------------------------------------

typedef __attribute__((ext_vector_type(8))) __bf16 bf16x8;
typedef __attribute__((ext_vector_type(4))) __bf16 bf16x4;
typedef __attribute__((ext_vector_type(4))) float f32x4;

#define MFMA16(A, B, C) __builtin_amdgcn_mfma_f32_16x16x32_bf16(A, B, C, 0, 0, 0)
#define BAR() asm volatile("s_barrier" ::: "memory")

#define T_SEQ 2048
#define D_MOD 1024

static __device__ __forceinline__ void gload_lds16(const void* g, void* l) {
  __builtin_amdgcn_global_load_lds(
      (const __attribute__((address_space(1))) void*)g,
      (__attribute__((address_space(3))) void*)l, 16, 0, 0);
}

// ------------------------- elementwise fp32 -> bf16 ------------------------
__global__ void cvt_bf16_kernel(const float* __restrict__ in,
                                __bf16* __restrict__ out, int n8) {
  int i = blockIdx.x * blockDim.x + threadIdx.x;
  if (i < n8) {
    const float4* p = (const float4*)(in + (size_t)i * 8);
    float4 a = p[0], b = p[1];
    bf16x8 o;
    o[0] = (__bf16)a.x; o[1] = (__bf16)a.y; o[2] = (__bf16)a.z; o[3] = (__bf16)a.w;
    o[4] = (__bf16)b.x; o[5] = (__bf16)b.y; o[6] = (__bf16)b.z; o[7] = (__bf16)b.w;
    *(bf16x8*)(out + (size_t)i * 8) = o;
  }
}

// ---------- all four W (K x N fp32) -> Wt (N x K bf16), one launch ---------
__global__ void transpose_cvt4_kernel(const float* __restrict__ Wq,
                                      const float* __restrict__ Wk,
                                      const float* __restrict__ Wv,
                                      const float* __restrict__ Wo,
                                      __bf16* __restrict__ Wqkvt,
                                      __bf16* __restrict__ Wot) {
  __shared__ float tile[32][33];
  const int z = blockIdx.z;
  const float* W = (z == 0) ? Wq : (z == 1) ? Wk : (z == 2) ? Wv : Wo;
  __bf16* Wt = (z < 3) ? (Wqkvt + (size_t)z * 1024 * 1024) : Wot;
  int tx = threadIdx.x, ty = threadIdx.y;
  int bx = blockIdx.x * 32, by = blockIdx.y * 32;
#pragma unroll
  for (int i = 0; i < 4; i++)
    tile[ty + 8 * i][tx] = W[(size_t)(by + ty + 8 * i) * D_MOD + bx + tx];
  __syncthreads();
#pragma unroll
  for (int i = 0; i < 4; i++)
    Wt[(size_t)(bx + ty + 8 * i) * D_MOD + by + tx] = (__bf16)tile[tx][ty + 8 * i];
}

// ========== QKV: 128x384 3-section register-pipelined GEMM, 512 WGs ========
// Per tile t (p = t&1):
//  sec1: read bg1(t) from p          ; MFMA g0 (a_c x b0_c)          ; BAR
//  sec2: read bg2(t) from p; STAGE_A(t+2)->p; MFMA g1;
//        vmcnt(t+2<NT ? 2 : 0)  [lands A(t+1)+B(t+1)]                ; BAR
//  sec3: read a(t+1),bg0(t+1) from p^1; STAGE_B(t+2)x3->p; MFMA g2   ; BAR
// Reads in each section are independent of that section's MFMA -> overlap.
// Ledger (issue order/wave): ... A(t+1)@sec2(t-1), B(t+1)x6@sec3(t-1),
// A(t+2)@sec2(t) -> vmcnt(2) drains A(t+1)+B(t+1). Restage safety: all
// reads of a region drain at the barrier closing their section (compiler
// lgkmcnt before s_barrier), strictly before the region's next DMA.
__global__ __launch_bounds__(512, 2) void qkv384_kernel(
    const __bf16* __restrict__ A, const __bf16* __restrict__ Bt,
    const float* __restrict__ bq, const float* __restrict__ bk,
    const float* __restrict__ bv, __bf16* __restrict__ Qo,
    __bf16* __restrict__ Ko, __bf16* __restrict__ Vto) {
  constexpr int NT = 16;  // K = 1024
  __shared__ __align__(16) char lds[131072];
#define ABUF(p) (lds + (p) * 16384)
#define BBUF(p) (lds + 32768 + (p) * 49152)

  const int tid = threadIdx.x;
  const int w = tid >> 6, l = tid & 63;
  const int wr = w >> 2, wc = w & 3;  // 2M x 4N
  const int cpx = gridDim.x >> 3;  // XCD bijective swizzle (512 % 8 == 0)
  const int swz = ((int)blockIdx.x & 7) * cpx + ((int)blockIdx.x >> 3);
  const int bm = (swz >> 3) * 128;   // 64 m-tiles
  const int bn = (swz & 7) * 384;    // 8 n-tiles

  const int cswz = (l & 3) ^ ((l >> 3) & 3);           // staging src chunk
  const int rlo = l & 15;                              // frag row within 16
  const int xsw = (((l >> 4) ^ ((l >> 1) & 3)) << 4);  // frag read chunk

#define STAGE_A(t, p)                                                     \
  {                                                                       \
    const __bf16* g = A + (size_t)(bm + w * 16 + (l >> 2)) * 1024 +       \
                      (t) * 64 + cswz * 8;                                \
    char* d = ABUF(p) + w * 1024 + l * 16;                                \
    gload_lds16(g, d);                                                    \
    gload_lds16(g + 32, d + 8192);                                        \
  }
#define STAGE_B(t, p, gch)                                                \
  {                                                                       \
    const __bf16* g = Bt +                                                \
        (size_t)(bn + ((gch) * 8 + w) * 16 + (l >> 2)) * 1024 +           \
        (t) * 64 + cswz * 8;                                              \
    char* d = BBUF(p) + ((gch) * 8 + w) * 1024 + l * 16;                  \
    gload_lds16(g, d);                                                    \
    gload_lds16(g + 32, d + 24576);                                       \
  }
#define LDA_FRAG(p, i, kk)                                        \
  (*(const bf16x8*)(ABUF(p) + (kk) * 8192 +                       \
                    (wr * 64 + (i) * 16 + rlo) * 64 + xsw))
#define LDB_FRAG(p, gch, n, kk)                                   \
  (*(const bf16x8*)(BBUF(p) + (kk) * 24576 +                      \
                    (wc * 96 + (gch) * 32 + (n) * 16 + rlo) * 64 + xsw))

  f32x4 acc[4][6] = {};
  bf16x8 a_c[4][2], a_n[4][2], b0_c[2][2], b0_n[2][2], b1f[2][2], b2f[2][2];

  // prologue: stage tiles 0 and 1 fully; land tile 0; preload a(0), bg0(0)
  STAGE_A(0, 0);
  STAGE_B(0, 0, 0); STAGE_B(0, 0, 1); STAGE_B(0, 0, 2);
  STAGE_A(1, 1);
  STAGE_B(1, 1, 0); STAGE_B(1, 1, 1); STAGE_B(1, 1, 2);
  asm volatile("s_waitcnt vmcnt(8)" ::: "memory");  // A(0)+B(0) landed
  BAR();
#pragma unroll
  for (int i = 0; i < 4; i++) {
    a_c[i][0] = LDA_FRAG(0, i, 0);
    a_c[i][1] = LDA_FRAG(0, i, 1);
  }
#pragma unroll
  for (int n = 0; n < 2; n++) {
    b0_c[n][0] = LDB_FRAG(0, 0, n, 0);
    b0_c[n][1] = LDB_FRAG(0, 0, n, 1);
  }

  for (int t = 0; t < NT; ++t) {
    const int p = t & 1;
    // ---- sec1: read bg1(t); MFMA g0 ----
#pragma unroll
    for (int n = 0; n < 2; n++) {
      b1f[n][0] = LDB_FRAG(p, 1, n, 0);
      b1f[n][1] = LDB_FRAG(p, 1, n, 1);
    }
    __builtin_amdgcn_s_setprio(1);
#pragma unroll
    for (int i = 0; i < 4; i++)
#pragma unroll
      for (int n = 0; n < 2; n++) {
        acc[i][n] = MFMA16(a_c[i][0], b0_c[n][0], acc[i][n]);
        acc[i][n] = MFMA16(a_c[i][1], b0_c[n][1], acc[i][n]);
      }
    __builtin_amdgcn_s_setprio(0);
    BAR();
    // ---- sec2: read bg2(t); stage A(t+2); MFMA g1; counted vmcnt ----
#pragma unroll
    for (int n = 0; n < 2; n++) {
      b2f[n][0] = LDB_FRAG(p, 2, n, 0);
      b2f[n][1] = LDB_FRAG(p, 2, n, 1);
    }
    if (t + 2 < NT) STAGE_A(t + 2, p);
    __builtin_amdgcn_s_setprio(1);
#pragma unroll
    for (int i = 0; i < 4; i++)
#pragma unroll
      for (int n = 0; n < 2; n++) {
        acc[i][2 + n] = MFMA16(a_c[i][0], b1f[n][0], acc[i][2 + n]);
        acc[i][2 + n] = MFMA16(a_c[i][1], b1f[n][1], acc[i][2 + n]);
      }
    __builtin_amdgcn_s_setprio(0);
    if (t + 2 < NT) asm volatile("s_waitcnt vmcnt(2)" ::: "memory");
    else asm volatile("s_waitcnt vmcnt(0)" ::: "memory");
    BAR();
    // ---- sec3: read a(t+1)+bg0(t+1) from p^1; stage B(t+2); MFMA g2 ----
    if (t + 1 < NT) {
#pragma unroll
      for (int i = 0; i < 4; i++) {
        a_n[i][0] = LDA_FRAG(p ^ 1, i, 0);
        a_n[i][1] = LDA_FRAG(p ^ 1, i, 1);
      }
#pragma unroll
      for (int n = 0; n < 2; n++) {
        b0_n[n][0] = LDB_FRAG(p ^ 1, 0, n, 0);
        b0_n[n][1] = LDB_FRAG(p ^ 1, 0, n, 1);
      }
    }
    if (t + 2 < NT) {
      STAGE_B(t + 2, p, 0); STAGE_B(t + 2, p, 1); STAGE_B(t + 2, p, 2);
    }
    __builtin_amdgcn_s_setprio(1);
#pragma unroll
    for (int i = 0; i < 4; i++)
#pragma unroll
      for (int n = 0; n < 2; n++) {
        acc[i][4 + n] = MFMA16(a_c[i][0], b2f[n][0], acc[i][4 + n]);
        acc[i][4 + n] = MFMA16(a_c[i][1], b2f[n][1], acc[i][4 + n]);
      }
    __builtin_amdgcn_s_setprio(0);
    BAR();
    // ---- swap pipelined registers ----
    if (t + 1 < NT) {
#pragma unroll
      for (int i = 0; i < 4; i++) {
        a_c[i][0] = a_n[i][0];
        a_c[i][1] = a_n[i][1];
      }
#pragma unroll
      for (int n = 0; n < 2; n++) {
        b0_c[n][0] = b0_n[n][0];
        b0_c[n][1] = b0_n[n][1];
      }
    }
  }

  // ---- epilogue: Q/K row-major; V segment transposed to Vt[b][d][t] ----
  const int l4 = (l >> 4) * 4;
#pragma unroll
  for (int gch = 0; gch < 3; gch++)
#pragma unroll
    for (int n = 0; n < 2; n++) {
      const int cbase = bn + wc * 96 + gch * 32 + n * 16;  // mult of 16
      const int seg = cbase >> 10;
      const int lcol = (cbase & 1023) + rlo;
      const int an = gch * 2 + n;
      if (seg < 2) {
        const float* bs = seg ? bk : bq;
        __bf16* os = seg ? Ko : Qo;
        const float bvv = bs[lcol];
#pragma unroll
        for (int i = 0; i < 4; i++) {
          const int rowb = bm + wr * 64 + i * 16 + l4;
#pragma unroll
          for (int r = 0; r < 4; r++)
            os[(size_t)(rowb + r) * D_MOD + lcol] =
                (__bf16)(acc[i][an][r] + bvv);
        }
      } else {
        const float bvv = bv[lcol];
#pragma unroll
        for (int i = 0; i < 4; i++) {
          const int rowb = bm + wr * 64 + i * 16 + l4;  // mult of 4
          const int z = rowb >> 11, tt = rowb & 2047;
          bf16x4 pk;
#pragma unroll
          for (int r = 0; r < 4; r++) pk[r] = (__bf16)(acc[i][an][r] + bvv);
          *(bf16x4*)(Vto + (size_t)z * (D_MOD * T_SEQ) +
                     (size_t)lcol * T_SEQ + tt) = pk;
        }
      }
    }
#undef ABUF
#undef BBUF
#undef STAGE_A
#undef STAGE_B
#undef LDA_FRAG
#undef LDB_FRAG
}

// ================= 256^2 8-phase GEMM (QK: causal, f32 out) ================
template <int MG, int NG>
static __device__ __forceinline__ void mfma_quad(f32x4 (&acc)[8][4],
                                                 const bf16x8 (&aR)[4][2],
                                                 const bf16x8 (&bR)[2][2]) {
#pragma unroll
  for (int i = 0; i < 4; i++)
#pragma unroll
    for (int n = 0; n < 2; n++)
#pragma unroll
      for (int kk = 0; kk < 2; kk++)
        acc[MG * 4 + i][NG * 2 + n] =
            MFMA16(aR[i][kk], bR[n][kk], acc[MG * 4 + i][NG * 2 + n]);
}

__global__ __launch_bounds__(512, 2) void qk_kernel(
    const __bf16* __restrict__ A, const __bf16* __restrict__ Bt,
    float* __restrict__ So, size_t bsA, size_t bsB, size_t bsC) {
  constexpr int NT = 16;
  __shared__ __align__(16) char lds[131072];
#define ABUF(p, h) (lds + ((p) * 2 + (h)) * 16384)
#define BBUF(p, h) (lds + 65536 + ((p) * 2 + (h)) * 16384)

  const int tid = threadIdx.x;
  const int w = tid >> 6, l = tid & 63;
  const int wr = w >> 2, wc = w & 3;
  if ((int)blockIdx.y > (int)blockIdx.x) return;
  const int bm = blockIdx.x * 256, bn = blockIdx.y * 256;
  const int z = blockIdx.z;
  A += (size_t)z * bsA;
  Bt += (size_t)z * bsB;

  const int grow = l >> 2;
  const int cswz = (l & 3) ^ ((l >> 3) & 3);
  const int rlo = l & 15;
  const int xsw = (((l >> 4) ^ ((l >> 1) & 3)) << 4);

#define STAGE_A(t, h)                                                       \
  {                                                                         \
    const __bf16* g = A + (size_t)(bm + (h) * 128 + w * 16 + grow) * 1024 + \
                      (t) * 64 + cswz * 8;                                  \
    char* d = ABUF((t) & 1, h) + w * 1024 + l * 16;                         \
    gload_lds16(g, d);                                                      \
    gload_lds16(g + 32, d + 8192);                                          \
  }
#define STAGE_B(t, h)                                                       \
  {                                                                         \
    const __bf16* g = Bt + (size_t)(bn + (h) * 128 + w * 16 + grow) * 1024 +\
                      (t) * 64 + cswz * 8;                                  \
    char* d = BBUF((t) & 1, h) + w * 1024 + l * 16;                         \
    gload_lds16(g, d);                                                      \
    gload_lds16(g + 32, d + 8192);                                          \
  }
#define LDA_FRAG(p, g, i, kk)                                     \
  (*(const bf16x8*)(ABUF(p, wr) + (kk) * 8192 +                   \
                    ((g) * 64 + (i) * 16 + rlo) * 64 + xsw))
#define LDB_FRAG(p, g, n, kk)                                     \
  (*(const bf16x8*)(BBUF(p, (wc >> 1)) + (kk) * 8192 +            \
                    ((wc & 1) * 64 + (g) * 32 + (n) * 16 + rlo) * 64 + xsw))

  f32x4 acc[8][4] = {};
  STAGE_A(0, 0); STAGE_A(0, 1);
  STAGE_B(0, 0); STAGE_B(0, 1);
  STAGE_A(1, 0); STAGE_A(1, 1);
  asm volatile("s_waitcnt vmcnt(4)" ::: "memory");
  BAR();

  for (int t = 0; t < NT; ++t) {
    const int p = t & 1;
    bf16x8 a[4][2], b[2][2];
#pragma unroll
    for (int i = 0; i < 4; i++) {
      a[i][0] = LDA_FRAG(p, 0, i, 0);
      a[i][1] = LDA_FRAG(p, 0, i, 1);
    }
#pragma unroll
    for (int n = 0; n < 2; n++) {
      b[n][0] = LDB_FRAG(p, 0, n, 0);
      b[n][1] = LDB_FRAG(p, 0, n, 1);
    }
    if (t + 1 < NT) STAGE_B(t + 1, 0);
    BAR();
    __builtin_amdgcn_s_setprio(1);
    mfma_quad<0, 0>(acc, a, b);
    __builtin_amdgcn_s_setprio(0);
    BAR();
    bf16x8 b2[2][2];
#pragma unroll
    for (int n = 0; n < 2; n++) {
      b2[n][0] = LDB_FRAG(p, 1, n, 0);
      b2[n][1] = LDB_FRAG(p, 1, n, 1);
    }
    if (t + 1 < NT) STAGE_B(t + 1, 1);
    BAR();
    __builtin_amdgcn_s_setprio(1);
    mfma_quad<0, 1>(acc, a, b2);
    __builtin_amdgcn_s_setprio(0);
    BAR();
#pragma unroll
    for (int i = 0; i < 4; i++) {
      a[i][0] = LDA_FRAG(p, 1, i, 0);
      a[i][1] = LDA_FRAG(p, 1, i, 1);
    }
    BAR();
    __builtin_amdgcn_s_setprio(1);
    mfma_quad<1, 1>(acc, a, b2);
    __builtin_amdgcn_s_setprio(0);
    BAR();
#pragma unroll
    for (int n = 0; n < 2; n++) {
      b[n][0] = LDB_FRAG(p, 0, n, 0);
      b[n][1] = LDB_FRAG(p, 0, n, 1);
    }
    if (t + 2 < NT) {
      STAGE_A(t + 2, 0); STAGE_A(t + 2, 1);
      BAR();
      __builtin_amdgcn_s_setprio(1);
      mfma_quad<1, 0>(acc, a, b);
      __builtin_amdgcn_s_setprio(0);
      asm volatile("s_waitcnt vmcnt(4)" ::: "memory");
      BAR();
    } else {
      BAR();
      __builtin_amdgcn_s_setprio(1);
      mfma_quad<1, 0>(acc, a, b);
      __builtin_amdgcn_s_setprio(0);
      asm volatile("s_waitcnt vmcnt(0)" ::: "memory");
      BAR();
    }
  }

  float* os = So + (size_t)z * bsC;
#pragma unroll
  for (int n4 = 0; n4 < 4; n4++) {
    int col = bn + wc * 64 + n4 * 16 + rlo;
#pragma unroll
    for (int mi = 0; mi < 8; mi++) {
      int rowb = bm + wr * 128 + mi * 16 + (l >> 4) * 4;
#pragma unroll
      for (int r = 0; r < 4; r++) {
        int row = rowb + r;
        float v = acc[mi][n4][r] * 0.03125f;  // 1/sqrt(1024)
        if (col > row) v = -1e30f;
        os[(size_t)row * T_SEQ + col] = v;
      }
    }
  }
#undef ABUF
#undef BBUF
#undef STAGE_A
#undef STAGE_B
#undef LDA_FRAG
#undef LDB_FRAG
}

// ======== PV: 128x128 paired-triangular GEMM (34 BK-steps/WG, 1 round) =====
// WG (pid, nc, z): row-blocks pid and 15-pid of batch z, cols nc*128.
// A = P (bf16, lda=4096), Bt = Vt (ldb=2048), K_seg = (i+1)*128 exact.
// Triple-buffer (A 3x16KB + B 3x16KB = 96KB), 4 loads/tile, vmcnt(4).
__global__ __launch_bounds__(512, 2) void pv_kernel(
    const __bf16* __restrict__ Ap, const __bf16* __restrict__ Btp,
    __bf16* __restrict__ Op, size_t bsA, size_t bsB, size_t bsC) {
  __shared__ __align__(16) char lds[98304];
#define ABUF(p3) (lds + (p3) * 16384)
#define BBUF(p3) (lds + 49152 + (p3) * 16384)

  const int tid = threadIdx.x;
  const int w = tid >> 6, l = tid & 63;
  const int wr = w >> 2, wc = w & 3;  // 2M x 4N; wave tile 64x32
  const int pid = (int)blockIdx.x >> 3;
  const int bn = ((int)blockIdx.x & 7) * 128;
  const int z = blockIdx.z;
  const __bf16* A = Ap + (size_t)z * bsA;
  const __bf16* Bt = Btp + (size_t)z * bsB;
  __bf16* O = Op + (size_t)z * bsC;

  const int grow = w * 16 + (l >> 2);
  const int cswz = (l & 3) ^ ((l >> 3) & 3);
  const int rlo = l & 15;
  const int xsw = (((l >> 4) ^ ((l >> 1) & 3)) << 4);

#define PSTAGE_A(t, p3)                                                      \
  {                                                                          \
    const __bf16* g = A + (size_t)(bm + grow) * 4096 + (t) * 64 + cswz * 8;  \
    char* d = ABUF(p3) + w * 1024 + l * 16;                                  \
    gload_lds16(g, d);                                                       \
    gload_lds16(g + 32, d + 8192);                                           \
  }
#define PSTAGE_B(t, p3)                                                      \
  {                                                                          \
    const __bf16* g = Bt + (size_t)(bn + grow) * 2048 + (t) * 64 + cswz * 8; \
    char* d = BBUF(p3) + w * 1024 + l * 16;                                  \
    gload_lds16(g, d);                                                       \
    gload_lds16(g + 32, d + 8192);                                           \
  }
#define PLDA(p3, i, kk)                                           \
  (*(const bf16x8*)(ABUF(p3) + (kk) * 8192 +                      \
                    (wr * 64 + (i) * 16 + rlo) * 64 + xsw))
#define PLDB(p3, n, kk)                                           \
  (*(const bf16x8*)(BBUF(p3) + (kk) * 8192 +                      \
                    (wc * 32 + (n) * 16 + rlo) * 64 + xsw))

#pragma unroll
  for (int seg = 0; seg < 2; ++seg) {
    const int i = seg ? (15 - pid) : pid;
    const int bm = i * 128;
    const int NT = (i + 1) * 2;  // BK=64 steps over K=(i+1)*128
    f32x4 acc[4][2] = {};

    PSTAGE_A(0, 0); PSTAGE_B(0, 0);
    if (NT > 1) { PSTAGE_A(1, 1); PSTAGE_B(1, 1); }
    asm volatile("s_waitcnt vmcnt(4)" ::: "memory");
    BAR();

    int p = 0, pn2 = 2;
    for (int t = 0; t < NT; ++t) {
      bf16x8 af[4][2], bfv[2][2];
#pragma unroll
      for (int m = 0; m < 4; m++) {
        af[m][0] = PLDA(p, m, 0);
        af[m][1] = PLDA(p, m, 1);
      }
#pragma unroll
      for (int n = 0; n < 2; n++) {
        bfv[n][0] = PLDB(p, n, 0);
        bfv[n][1] = PLDB(p, n, 1);
      }
      if (t + 2 < NT) { PSTAGE_A(t + 2, pn2); PSTAGE_B(t + 2, pn2); }
      BAR();
      __builtin_amdgcn_s_setprio(1);
#pragma unroll
      for (int m = 0; m < 4; m++)
#pragma unroll
        for (int n = 0; n < 2; n++) {
          acc[m][n] = MFMA16(af[m][0], bfv[n][0], acc[m][n]);
          acc[m][n] = MFMA16(af[m][1], bfv[n][1], acc[m][n]);
        }
      __builtin_amdgcn_s_setprio(0);
      if (t + 2 < NT) asm volatile("s_waitcnt vmcnt(4)" ::: "memory");
      else asm volatile("s_waitcnt vmcnt(0)" ::: "memory");
      BAR();
      p = (p + 1 == 3) ? 0 : p + 1;
      pn2 = (pn2 + 1 == 3) ? 0 : pn2 + 1;
    }

    // epilogue: 128x128 bf16 tile
#pragma unroll
    for (int n = 0; n < 2; n++) {
      int col = bn + wc * 32 + n * 16 + rlo;
#pragma unroll
      for (int m = 0; m < 4; m++) {
        int rowb = bm + wr * 64 + m * 16 + (l >> 4) * 4;
#pragma unroll
        for (int r = 0; r < 4; r++)
          O[(size_t)(rowb + r) * D_MOD + col] = (__bf16)acc[m][n][r];
      }
    }
    BAR();  // LDS safe before next segment restage (epilogue uses no LDS)
  }
#undef ABUF
#undef BBUF
#undef PSTAGE_A
#undef PSTAGE_B
#undef PLDA
#undef PLDB
}

// ============ 128x256 triple-buffer GEMM (out-proj, f32 out + bias) ========
__global__ __launch_bounds__(512, 2) void oproj_kernel(
    const __bf16* __restrict__ A, const __bf16* __restrict__ Bt,
    const float* __restrict__ b0, float* __restrict__ o0) {
  constexpr int NT = 16;
  __shared__ __align__(16) char lds[147456];
#define ABUF(p3) (lds + (p3) * 16384)
#define BBUF(p3) (lds + 49152 + (p3) * 32768)

  const int tid = threadIdx.x;
  const int w = tid >> 6, l = tid & 63;
  const int wr = w >> 2, wc = w & 3;
  const int cpx = gridDim.x >> 3;
  const int swz = ((int)blockIdx.x & 7) * cpx + ((int)blockIdx.x >> 3);
  const int bm = (swz >> 2) * 128, bn = (swz & 3) * 256;

  const int grow = w * 16 + (l >> 2);
  const int cswz = (l & 3) ^ ((l >> 3) & 3);
  const int rlo = l & 15;
  const int xsw = (((l >> 4) ^ ((l >> 1) & 3)) << 4);

#define STAGE_A(t, p3)                                                       \
  {                                                                          \
    const __bf16* g = A + (size_t)(bm + grow) * 1024 + (t) * 64 + cswz * 8;  \
    char* d = ABUF(p3) + w * 1024 + l * 16;                                  \
    gload_lds16(g, d);                                                       \
    gload_lds16(g + 32, d + 8192);                                           \
  }
#define STAGE_B(t, p3)                                                       \
  {                                                                          \
    const __bf16* g = Bt + (size_t)(bn + grow) * 1024 + (t) * 64 + cswz * 8; \
    char* d = BBUF(p3) + w * 1024 + l * 16;                                  \
    gload_lds16(g, d);                                                       \
    gload_lds16(g + 32, d + 16384);                                          \
    const __bf16* g2 = g + (size_t)128 * 1024;                               \
    gload_lds16(g2, d + 8192);                                               \
    gload_lds16(g2 + 32, d + 8192 + 16384);                                  \
  }
#define LDA_FRAG(p3, i, kk)                                       \
  (*(const bf16x8*)(ABUF(p3) + (kk) * 8192 +                      \
                    (wr * 64 + (i) * 16 + rlo) * 64 + xsw))
#define LDB_FRAG(p3, n, kk)                                       \
  (*(const bf16x8*)(BBUF(p3) + (kk) * 16384 +                     \
                    (wc * 64 + (n) * 16 + rlo) * 64 + xsw))

  f32x4 acc[4][4] = {};
  STAGE_A(0, 0); STAGE_B(0, 0);
  STAGE_A(1, 1); STAGE_B(1, 1);
  asm volatile("s_waitcnt vmcnt(6)" ::: "memory");
  BAR();

  int p = 0, pn2 = 2;
  for (int t = 0; t < NT; ++t) {
    bf16x8 af[4][2], bf01[2][2], bf23[2][2];
#pragma unroll
    for (int i = 0; i < 4; i++) {
      af[i][0] = LDA_FRAG(p, i, 0);
      af[i][1] = LDA_FRAG(p, i, 1);
    }
#pragma unroll
    for (int n = 0; n < 2; n++) {
      bf01[n][0] = LDB_FRAG(p, n, 0);
      bf01[n][1] = LDB_FRAG(p, n, 1);
    }
    if (t + 2 < NT) STAGE_A(t + 2, pn2);
    BAR();
    __builtin_amdgcn_s_setprio(1);
#pragma unroll
    for (int i = 0; i < 4; i++)
#pragma unroll
      for (int n = 0; n < 2; n++) {
        acc[i][n] = MFMA16(af[i][0], bf01[n][0], acc[i][n]);
        acc[i][n] = MFMA16(af[i][1], bf01[n][1], acc[i][n]);
      }
    __builtin_amdgcn_s_setprio(0);
    BAR();
#pragma unroll
    for (int n = 0; n < 2; n++) {
      bf23[n][0] = LDB_FRAG(p, n + 2, 0);
      bf23[n][1] = LDB_FRAG(p, n + 2, 1);
    }
    if (t + 2 < NT) STAGE_B(t + 2, pn2);
    BAR();
    __builtin_amdgcn_s_setprio(1);
#pragma unroll
    for (int i = 0; i < 4; i++)
#pragma unroll
      for (int n = 0; n < 2; n++) {
        acc[i][n + 2] = MFMA16(af[i][0], bf23[n][0], acc[i][n + 2]);
        acc[i][n + 2] = MFMA16(af[i][1], bf23[n][1], acc[i][n + 2]);
      }
    __builtin_amdgcn_s_setprio(0);
    if (t + 2 < NT) {
      asm volatile("s_waitcnt vmcnt(6)" ::: "memory");
    } else {
      asm volatile("s_waitcnt vmcnt(0)" ::: "memory");
    }
    BAR();
    p = (p + 1 == 3) ? 0 : p + 1;
    pn2 = (pn2 + 1 == 3) ? 0 : pn2 + 1;
  }

#pragma unroll
  for (int n = 0; n < 4; n++) {
    int col = bn + wc * 64 + n * 16 + rlo;
    float bvv = b0[col];
#pragma unroll
    for (int m = 0; m < 4; m++) {
      int rowb = bm + wr * 64 + m * 16 + (l >> 4) * 4;
#pragma unroll
      for (int r = 0; r < 4; r++)
        o0[(size_t)(rowb + r) * D_MOD + col] = acc[m][n][r] + bvv;
    }
  }
#undef ABUF
#undef BBUF
#undef STAGE_A
#undef STAGE_B
#undef LDA_FRAG
#undef LDB_FRAG
}

// ----------------------- row softmax, P bf16 in-place ----------------------
__global__ __launch_bounds__(256) void softmax_kernel(float* __restrict__ S,
                                                      size_t bstride) {
  const int t = blockIdx.x, b = blockIdx.y;
  float* Srow = S + (size_t)b * bstride + (size_t)t * T_SEQ;
  __bf16* Prow = (__bf16*)Srow;
  const int L = ((t + 1) + 127) & ~127;
  const int tid = threadIdx.x;
  const int base = tid * 8;
  const bool act = base < L;
  float v[8];
  float m = -1e30f;
  if (act) {
    float4 a = *(const float4*)(Srow + base);
    float4 c = *(const float4*)(Srow + base + 4);
    v[0] = a.x; v[1] = a.y; v[2] = a.z; v[3] = a.w;
    v[4] = c.x; v[5] = c.y; v[6] = c.z; v[7] = c.w;
#pragma unroll
    for (int j = 0; j < 8; j++) m = fmaxf(m, v[j]);
  }
#pragma unroll
  for (int off = 1; off < 64; off <<= 1) m = fmaxf(m, __shfl_xor(m, off));
  __shared__ float redm[4], reds[4];
  const int wave = tid >> 6, lane = tid & 63;
  if (lane == 0) redm[wave] = m;
  __syncthreads();
  m = fmaxf(fmaxf(redm[0], redm[1]), fmaxf(redm[2], redm[3]));
  float p[8];
  float s = 0.f;
  if (act) {
#pragma unroll
    for (int j = 0; j < 8; j++) {
      p[j] = __expf(v[j] - m);
      s += p[j];
    }
  }
#pragma unroll
  for (int off = 1; off < 64; off <<= 1) s += __shfl_xor(s, off);
  if (lane == 0) reds[wave] = s;
  __syncthreads();  // fences: reads done before in-place bf16 writes
  const float inv = 1.0f / (reds[0] + reds[1] + reds[2] + reds[3]);
  if (act) {
    bf16x8 o;
#pragma unroll
    for (int j = 0; j < 8; j++) o[j] = (__bf16)(p[j] * inv);
    *(bf16x8*)(Prow + base) = o;
  }
}

// ---------------------------------------------------------------------------
extern "C" void kernel_launch(void* const* d_in, const int* in_sizes, int n_in,
                              void* d_out, int out_size, void* d_ws,
                              size_t ws_size, hipStream_t stream) {
  const float* x = (const float*)d_in[0];
  const float* Wq = (const float*)d_in[1];
  const float* bq = (const float*)d_in[2];
  const float* Wk = (const float*)d_in[3];
  const float* bk = (const float*)d_in[4];
  const float* Wv = (const float*)d_in[5];
  const float* bv = (const float*)d_in[6];
  const float* Wo = (const float*)d_in[7];
  const float* bo = (const float*)d_in[8];

  char* ws = (char*)d_ws;
  const size_t MB = 1u << 20;
  const size_t TC = (size_t)T_SEQ * D_MOD;  // 2M elems / batch
  const size_t TT = (size_t)T_SEQ * T_SEQ;  // 4M elems / batch
  __bf16* xb    = (__bf16*)(ws);            // [0,16) MB ; dead after QKV
  __bf16* Wqkvt = (__bf16*)(ws + 16 * MB);  // [16,22)  3072x1024
  __bf16* Wot   = (__bf16*)(ws + 22 * MB);  // [22,24)
  __bf16* Qb    = (__bf16*)(ws + 24 * MB);  // [24,40) ; later AO
  __bf16* Kb    = (__bf16*)(ws + 40 * MB);  // [40,56)
  __bf16* Vtb   = (__bf16*)(ws + 56 * MB);  // [56,72)  V^T direct from QKV

  // 1) x -> bf16
  cvt_bf16_kernel<<<4096, 256, 0, stream>>>(x, xb, 8192 * D_MOD / 8);
  // 2) weight transposes (one dispatch)
  transpose_cvt4_kernel<<<dim3(32, 32, 4), dim3(32, 8), 0, stream>>>(
      Wq, Wk, Wv, Wo, Wqkvt, Wot);
  // 3) fused QKV projection (pipelined); V written transposed to Vtb
  qkv384_kernel<<<512, 512, 0, stream>>>(xb, Wqkvt, bq, bk, bv, Qb, Kb, Vtb);

  const bool batched = ws_size >= 137 * MB;
  if (batched) {
    float* S = (float*)(ws + 72 * MB);  // [72,136) fp32, 4 batches
    __bf16* AO = Qb;                    // Q dead after QK
    // 4) S = QK^T * scale, causal: 256^2 tiles, live j<=i
    qk_kernel<<<dim3(8, 8, 4), 512, 0, stream>>>(Qb, Kb, S, TC, TC, TT);
    // 5) row softmax, P bf16 in-place (row stride 4096 bf16)
    softmax_kernel<<<dim3(T_SEQ, 4), 256, 0, stream>>>(S, TT);
    // 6) O = P V, paired triangular 128x128 tiles (1 balanced round)
    pv_kernel<<<dim3(64, 1, 4), 512, 0, stream>>>((const __bf16*)S, Vtb, AO,
                                                  TT * 2, TC, TC);
    // 7) out projection (f32 out)
    oproj_kernel<<<256, 512, 0, stream>>>(AO, Wot, bo, (float*)d_out);
  } else {
    // per-batch fallback: S reuses xb region (dead after QKV), AO over Qb
    float* S = (float*)(ws);
    __bf16* AO = Qb;
    for (int b = 0; b < 4; ++b) {
      qk_kernel<<<dim3(8, 8, 1), 512, 0, stream>>>(Qb + b * TC, Kb + b * TC, S,
                                                   0, 0, 0);
      softmax_kernel<<<dim3(T_SEQ, 1), 256, 0, stream>>>(S, 0);
      pv_kernel<<<dim3(64, 1, 1), 512, 0, stream>>>(
          (const __bf16*)S, Vtb + b * TC, AO + b * TC, 0, 0, 0);
    }
    oproj_kernel<<<256, 512, 0, stream>>>(AO, Wot, bo, (float*)d_out);
  }
}